// Round 1
// baseline (1259.396 us; speedup 1.0000x reference)
//
#include <hip/hip_runtime.h>
#include <stdint.h>

// ---------------- problem constants ----------------
#define N_ROWS 4096      // bs*seq = 8*512
#define DDIM   512
#define KCODES 8192
#define NK     (N_ROWS * KCODES)   // 33,554,432
#define HALF_NK 16777216u          // NK/2
#define BS_F   8.0f
#define INV_N  (1.0f / 4096.0f)

// ---------------- ws layout (float offsets) ----------------
#define OFF_LOGIT   0
#define OFF_CNORM   (NK)
#define OFF_ROWM1   (OFF_CNORM + KCODES)
#define OFF_ROWS1   (OFF_ROWM1 + N_ROWS)
#define OFF_ROWM2   (OFF_ROWS1 + N_ROWS)
#define OFF_ROWS2   (OFF_ROWM2 + N_ROWS)
#define OFF_COLSUM  (OFF_ROWS2 + N_ROWS)
#define OFF_ACC     (OFF_COLSUM + KCODES)   // [0]=sum p*logp, [1]=sum (z-zhat)^2
#define WS_FLOATS   (OFF_ACC + 2)

// ---------------- JAX threefry2x32-20, key(42) = (0,42) ----------------
// Reproduces jax.random.uniform(key(42), (4096,8192)) bitwise.
__device__ __forceinline__ uint32_t rotl32(uint32_t x, int r) {
    return (x << r) | (x >> (32 - r));
}

__device__ __forceinline__ float jax_uniform(uint32_t j) {
    uint32_t c0, c1;
    bool second;
    if (j < HALF_NK) { c0 = j; c1 = j + HALF_NK; second = false; }
    else             { c0 = j - HALF_NK; c1 = j; second = true;  }
    const uint32_t ks0 = 0u, ks1 = 42u, ks2 = 0x1BD11BDAu ^ 0u ^ 42u;
    uint32_t x0 = c0 + ks0;
    uint32_t x1 = c1 + ks1;
#define TF_R(r) { x0 += x1; x1 = rotl32(x1, r); x1 ^= x0; }
    TF_R(13) TF_R(15) TF_R(26) TF_R(6)
    x0 += ks1; x1 += ks2 + 1u;
    TF_R(17) TF_R(29) TF_R(16) TF_R(24)
    x0 += ks2; x1 += ks0 + 2u;
    TF_R(13) TF_R(15) TF_R(26) TF_R(6)
    x0 += ks0; x1 += ks1 + 3u;
    TF_R(17) TF_R(29) TF_R(16) TF_R(24)
    x0 += ks1; x1 += ks2 + 4u;
    TF_R(13) TF_R(15) TF_R(26) TF_R(6)
    x0 += ks2; x1 += ks0 + 5u;
#undef TF_R
    uint32_t bits = second ? x1 : x0;
    return __uint_as_float((bits >> 9) | 0x3f800000u) - 1.0f;
}

__device__ __forceinline__ float gumbel_from_u(float u) {
    return -logf(-logf(u + 1e-10f) + 1e-10f);
}

// ---------------- block reduction helper (256 threads = 4 waves) ----------------
__device__ __forceinline__ float blockReduce(float v, float* red, bool ismax) {
    #pragma unroll
    for (int o = 32; o > 0; o >>= 1) {
        float t = __shfl_down(v, o);
        v = ismax ? fmaxf(v, t) : v + t;
    }
    __syncthreads();   // protect red[] reuse across successive calls
    if ((threadIdx.x & 63) == 0) red[threadIdx.x >> 6] = v;
    __syncthreads();
    return ismax ? fmaxf(fmaxf(red[0], red[1]), fmaxf(red[2], red[3]))
                 : (red[0] + red[1] + red[2] + red[3]);
}

// ---------------- K1: codebook row norms ----------------
__global__ __launch_bounds__(64) void k_cnorm(const float* __restrict__ cb,
                                              float* __restrict__ cnorm) {
    const int k = blockIdx.x;
    const int lane = threadIdx.x;
    const float* row = cb + (size_t)k * DDIM;
    float4 a = *(const float4*)(row + lane * 4);
    float4 b = *(const float4*)(row + 256 + lane * 4);
    float s = a.x*a.x + a.y*a.y + a.z*a.z + a.w*a.w
            + b.x*b.x + b.y*b.y + b.z*b.z + b.w*b.w;
    #pragma unroll
    for (int o = 32; o > 0; o >>= 1) s += __shfl_down(s, o);
    if (lane == 0) cnorm[k] = s;
}

// ---------------- K2: GEMM1 -> logit' = w*(2*z.c - |c|^2) ----------------
// (shift-invariant: |z|^2 per-row constant cancels in all softmax-derived outputs)
__global__ __launch_bounds__(256) void k_gemm1(const float* __restrict__ z,
                                               const float* __restrict__ cb,
                                               const float* __restrict__ cnorm,
                                               const float* __restrict__ var_q,
                                               float* __restrict__ logit) {
    __shared__ float As[16][68];
    __shared__ float Bs[16][68];
    const int t    = threadIdx.x;
    const int n0   = blockIdx.y * 64;
    const int k0   = blockIdx.x * 64;
    const int lrow = t >> 2;
    const int lcol = (t & 3) * 4;
    const int tx   = t & 15;
    const int ty   = t >> 4;
    float acc[4][4] = {};
    for (int kt = 0; kt < DDIM; kt += 16) {
        float4 av = *(const float4*)(z  + (size_t)(n0 + lrow) * DDIM + kt + lcol);
        float4 bv = *(const float4*)(cb + (size_t)(k0 + lrow) * DDIM + kt + lcol);
        As[lcol+0][lrow] = av.x; As[lcol+1][lrow] = av.y;
        As[lcol+2][lrow] = av.z; As[lcol+3][lrow] = av.w;
        Bs[lcol+0][lrow] = bv.x; Bs[lcol+1][lrow] = bv.y;
        Bs[lcol+2][lrow] = bv.z; Bs[lcol+3][lrow] = bv.w;
        __syncthreads();
        #pragma unroll
        for (int kk = 0; kk < 16; ++kk) {
            float4 a = *(const float4*)&As[kk][ty * 4];
            float4 b = *(const float4*)&Bs[kk][tx * 4];
            float av4[4] = {a.x, a.y, a.z, a.w};
            float bv4[4] = {b.x, b.y, b.z, b.w};
            #pragma unroll
            for (int i = 0; i < 4; ++i)
                #pragma unroll
                for (int jj = 0; jj < 4; ++jj)
                    acc[i][jj] = fmaf(av4[i], bv4[jj], acc[i][jj]);
        }
        __syncthreads();
    }
    const float w = 0.5f / fmaxf(var_q[0], 1e-10f);
    float4 cn = *(const float4*)(cnorm + k0 + tx * 4);
    float cn4[4] = {cn.x, cn.y, cn.z, cn.w};
    #pragma unroll
    for (int i = 0; i < 4; ++i) {
        float4 o;
        o.x = w * (2.0f * acc[i][0] - cn4[0]);
        o.y = w * (2.0f * acc[i][1] - cn4[1]);
        o.z = w * (2.0f * acc[i][2] - cn4[2]);
        o.w = w * (2.0f * acc[i][3] - cn4[3]);
        *(float4*)(logit + (size_t)(n0 + ty * 4 + i) * KCODES + k0 + tx * 4) = o;
    }
}

// ---------------- K3: per-row stats (softmax + gumbel-softmax) ----------------
// m1,s1 for probs; m2,s2 for encodings; accumulates sum(p*logp).
__global__ __launch_bounds__(256) void k_stats(const float* __restrict__ logit,
                                               float* __restrict__ rowm1,
                                               float* __restrict__ rows1,
                                               float* __restrict__ rowm2,
                                               float* __restrict__ rows2,
                                               float* __restrict__ acc) {
    __shared__ float sy[KCODES];   // (logit+g)/T
    __shared__ float red[4];
    const int n = blockIdx.x;
    const int t = threadIdx.x;
    const float* lrow = logit + (size_t)n * KCODES;
    float m1 = -3.0e38f, m2 = -3.0e38f;
    for (int c = t * 4; c < KCODES; c += 1024) {
        float4 v = *(const float4*)(lrow + c);
        float l4[4] = {v.x, v.y, v.z, v.w};
        float y4[4];
        #pragma unroll
        for (int i = 0; i < 4; ++i) {
            float u = jax_uniform((uint32_t)(n * KCODES + c + i));
            float g = gumbel_from_u(u);
            y4[i] = (l4[i] + g) * 2.0f;   // /T, T=0.5
            m1 = fmaxf(m1, l4[i]);
            m2 = fmaxf(m2, y4[i]);
        }
        *(float4*)&sy[c] = make_float4(y4[0], y4[1], y4[2], y4[3]);
    }
    m1 = blockReduce(m1, red, true);
    m2 = blockReduce(m2, red, true);
    float s1 = 0.0f, t1 = 0.0f, s2 = 0.0f;
    for (int c = t * 4; c < KCODES; c += 1024) {
        float4 v  = *(const float4*)(lrow + c);   // L2-warm re-read
        float4 yv = *(const float4*)&sy[c];
        float l4[4] = {v.x, v.y, v.z, v.w};
        float y4[4] = {yv.x, yv.y, yv.z, yv.w};
        #pragma unroll
        for (int i = 0; i < 4; ++i) {
            float x = l4[i] - m1;
            float e = expf(x);
            s1 += e;
            t1 += e * x;
            s2 += expf(y4[i] - m2);
        }
    }
    s1 = blockReduce(s1, red, false);
    t1 = blockReduce(t1, red, false);
    s2 = blockReduce(s2, red, false);
    if (t == 0) {
        rowm1[n] = m1; rows1[n] = s1;
        rowm2[n] = m2; rows2[n] = s2;
        atomicAdd(acc + 0, t1 / s1 - logf(s1));   // sum_k p*logp for this row
    }
}

// ---------------- K4: column sums of probs (for perplexity) ----------------
// Runs BEFORE logits are overwritten by encodings.
__global__ __launch_bounds__(256) void k_colsum(const float* __restrict__ logit,
                                                const float* __restrict__ rowm1,
                                                const float* __restrict__ rows1,
                                                float* __restrict__ colsum) {
    __shared__ float sm[256], ss[256];
    const int t  = threadIdx.x;
    const int c0 = blockIdx.x * 512;
    const int r0 = blockIdx.y * 256;
    sm[t] = rowm1[r0 + t];
    ss[t] = 1.0f / rows1[r0 + t];
    __syncthreads();
    float a0 = 0.0f, a1 = 0.0f;
    for (int r = 0; r < 256; ++r) {
        float2 v = *(const float2*)(logit + (size_t)(r0 + r) * KCODES + c0 + 2 * t);
        float m = sm[r], is = ss[r];
        a0 += expf(v.x - m) * is;
        a1 += expf(v.y - m) * is;
    }
    atomicAdd(&colsum[c0 + 2 * t],     a0);
    atomicAdd(&colsum[c0 + 2 * t + 1], a1);
}

// ---------------- K5: encodings (in-place over logit) ----------------
__global__ __launch_bounds__(256) void k_enc(float* __restrict__ logit,
                                             const float* __restrict__ rowm2,
                                             const float* __restrict__ rows2) {
    const int idx4 = (blockIdx.x * 256 + threadIdx.x) * 4;
    const int n = idx4 >> 13;   // /KCODES
    const float m2  = rowm2[n];
    const float inv = 1.0f / rows2[n];
    float4 v = *(float4*)(logit + idx4);
    float l4[4] = {v.x, v.y, v.z, v.w};
    float o4[4];
    #pragma unroll
    for (int i = 0; i < 4; ++i) {
        float u = jax_uniform((uint32_t)(idx4 + i));
        float g = gumbel_from_u(u);
        float y = (l4[i] + g) * 2.0f;
        o4[i] = expf(y - m2) * inv;
    }
    *(float4*)(logit + idx4) = make_float4(o4[0], o4[1], o4[2], o4[3]);
}

// ---------------- K6: GEMM2 z_hat = enc @ cb, fused (z-z_hat)^2 reduction ----
__global__ __launch_bounds__(256) void k_gemm2(const float* __restrict__ enc,
                                               const float* __restrict__ cb,
                                               const float* __restrict__ z,
                                               float* __restrict__ out,
                                               float* __restrict__ acc) {
    __shared__ float As[16][68];
    __shared__ float Bs[16][68];
    __shared__ float red[4];
    const int t    = threadIdx.x;
    const int n0   = blockIdx.y * 64;
    const int d0   = blockIdx.x * 64;
    const int lrow = t >> 2;
    const int lcol = (t & 3) * 4;
    const int krow = t >> 4;
    const int dc   = (t & 15) * 4;
    const int tx   = t & 15;
    const int ty   = t >> 4;
    float acc4[4][4] = {};
    for (int kt = 0; kt < KCODES; kt += 16) {
        float4 av = *(const float4*)(enc + (size_t)(n0 + lrow) * KCODES + kt + lcol);
        As[lcol+0][lrow] = av.x; As[lcol+1][lrow] = av.y;
        As[lcol+2][lrow] = av.z; As[lcol+3][lrow] = av.w;
        float4 bv = *(const float4*)(cb + (size_t)(kt + krow) * DDIM + d0 + dc);
        *(float4*)&Bs[krow][dc] = bv;
        __syncthreads();
        #pragma unroll
        for (int kk = 0; kk < 16; ++kk) {
            float4 a = *(const float4*)&As[kk][ty * 4];
            float4 b = *(const float4*)&Bs[kk][tx * 4];
            float av4[4] = {a.x, a.y, a.z, a.w};
            float bv4[4] = {b.x, b.y, b.z, b.w};
            #pragma unroll
            for (int i = 0; i < 4; ++i)
                #pragma unroll
                for (int jj = 0; jj < 4; ++jj)
                    acc4[i][jj] = fmaf(av4[i], bv4[jj], acc4[i][jj]);
        }
        __syncthreads();
    }
    float part = 0.0f;
    #pragma unroll
    for (int i = 0; i < 4; ++i) {
        const int n = n0 + ty * 4 + i;
        float4 zv = *(const float4*)(z + (size_t)n * DDIM + d0 + tx * 4);
        float4 o  = make_float4(acc4[i][0], acc4[i][1], acc4[i][2], acc4[i][3]);
        *(float4*)(out + (size_t)n * DDIM + d0 + tx * 4) = o;
        float dx = zv.x - o.x, dy = zv.y - o.y, dz = zv.z - o.z, dw = zv.w - o.w;
        part += dx*dx + dy*dy + dz*dz + dw*dw;
    }
    #pragma unroll
    for (int o = 32; o > 0; o >>= 1) part += __shfl_down(part, o);
    if ((t & 63) == 0) red[t >> 6] = part;
    __syncthreads();
    if (t == 0) atomicAdd(acc + 1, red[0] + red[1] + red[2] + red[3]);
}

// ---------------- K7: finalize loss + perplexity ----------------
__global__ __launch_bounds__(256) void k_final(const float* __restrict__ colsum,
                                               const float* __restrict__ acc,
                                               const float* __restrict__ var_q,
                                               float* __restrict__ out) {
    __shared__ float red[4];
    const int t = threadIdx.x;
    float s = 0.0f;
    for (int k = t; k < KCODES; k += 256) {
        float a = colsum[k] * INV_N;
        s += a * logf(a + 1e-7f);
    }
    s = blockReduce(s, red, false);
    if (t == 0) {
        float w = 0.5f / fmaxf(var_q[0], 1e-10f);
        float loss = acc[0] / BS_F + acc[1] * w / BS_F;
        out[(size_t)N_ROWS * DDIM]     = loss;
        out[(size_t)N_ROWS * DDIM + 1] = expf(-s);
    }
}

// ---------------- launch ----------------
extern "C" void kernel_launch(void* const* d_in, const int* in_sizes, int n_in,
                              void* d_out, int out_size, void* d_ws, size_t ws_size,
                              hipStream_t stream) {
    const float* z     = (const float*)d_in[0];
    const float* var_q = (const float*)d_in[1];
    const float* cb    = (const float*)d_in[2];
    float* out = (float*)d_out;
    float* ws  = (float*)d_ws;
    if (ws_size < (size_t)WS_FLOATS * sizeof(float)) return;  // need ~134.4 MB

    float* logit  = ws + OFF_LOGIT;
    float* cnorm  = ws + OFF_CNORM;
    float* rowm1  = ws + OFF_ROWM1;
    float* rows1  = ws + OFF_ROWS1;
    float* rowm2  = ws + OFF_ROWM2;
    float* rows2  = ws + OFF_ROWS2;
    float* colsum = ws + OFF_COLSUM;
    float* accp   = ws + OFF_ACC;

    // zero the accumulators (ws is poisoned 0xAA before every timed launch)
    hipMemsetAsync(colsum, 0, (KCODES + 2) * sizeof(float), stream);

    k_cnorm <<<KCODES, 64, 0, stream>>>(cb, cnorm);
    k_gemm1 <<<dim3(KCODES / 64, N_ROWS / 64), 256, 0, stream>>>(z, cb, cnorm, var_q, logit);
    k_stats <<<N_ROWS, 256, 0, stream>>>(logit, rowm1, rows1, rowm2, rows2, accp);
    k_colsum<<<dim3(KCODES / 512, N_ROWS / 256), 256, 0, stream>>>(logit, rowm1, rows1, colsum);
    k_enc   <<<NK / 1024, 256, 0, stream>>>(logit, rowm2, rows2);
    k_gemm2 <<<dim3(DDIM / 64, N_ROWS / 64), 256, 0, stream>>>(logit, cb, z, out, accp);
    k_final <<<1, 256, 0, stream>>>(colsum, accp, var_q, out);
}

// Round 2
// 678.027 us; speedup vs baseline: 1.8574x; 1.8574x over previous
//
#include <hip/hip_runtime.h>
#include <stdint.h>

// ---------------- problem constants ----------------
#define N_ROWS 4096      // bs*seq = 8*512
#define DDIM   512
#define KCODES 8192
#define NK     (N_ROWS * KCODES)   // 33,554,432
#define HALF_NK 16777216u          // NK/2
#define BS_F   8.0f
#define INV_N  (1.0f / 4096.0f)

// ---------------- ws layout (float offsets) ----------------
#define OFF_LOGIT   0
#define OFF_CNORM   (NK)
#define OFF_ROWM1   (OFF_CNORM + KCODES)
#define OFF_ROWS1   (OFF_ROWM1 + N_ROWS)
#define OFF_ROWM2   (OFF_ROWS1 + N_ROWS)
#define OFF_ROWS2   (OFF_ROWM2 + N_ROWS)
#define OFF_COLSUM  (OFF_ROWS2 + N_ROWS)
#define OFF_ACC     (OFF_COLSUM + KCODES)   // [0]=sum p*logp, [1]=sum (z-zhat)^2
#define WS_FLOATS   (OFF_ACC + 2)

typedef __attribute__((ext_vector_type(8))) short short8;
typedef __attribute__((ext_vector_type(4))) float f32x4;

// fp32 -> bf16 bits, round-to-nearest-even
__device__ __forceinline__ unsigned short f2bf(float x) {
    uint32_t u = __float_as_uint(x);
    u += 0x7fffu + ((u >> 16) & 1u);
    return (unsigned short)(u >> 16);
}

// ---------------- JAX threefry2x32-20, key(42) = (0,42) ----------------
__device__ __forceinline__ uint32_t rotl32(uint32_t x, int r) {
    return (x << r) | (x >> (32 - r));
}

__device__ __forceinline__ float jax_uniform(uint32_t j) {
    uint32_t c0, c1;
    bool second;
    if (j < HALF_NK) { c0 = j; c1 = j + HALF_NK; second = false; }
    else             { c0 = j - HALF_NK; c1 = j; second = true;  }
    const uint32_t ks0 = 0u, ks1 = 42u, ks2 = 0x1BD11BDAu ^ 0u ^ 42u;
    uint32_t x0 = c0 + ks0;
    uint32_t x1 = c1 + ks1;
#define TF_R(r) { x0 += x1; x1 = rotl32(x1, r); x1 ^= x0; }
    TF_R(13) TF_R(15) TF_R(26) TF_R(6)
    x0 += ks1; x1 += ks2 + 1u;
    TF_R(17) TF_R(29) TF_R(16) TF_R(24)
    x0 += ks2; x1 += ks0 + 2u;
    TF_R(13) TF_R(15) TF_R(26) TF_R(6)
    x0 += ks0; x1 += ks1 + 3u;
    TF_R(17) TF_R(29) TF_R(16) TF_R(24)
    x0 += ks1; x1 += ks2 + 4u;
    TF_R(13) TF_R(15) TF_R(26) TF_R(6)
    x0 += ks2; x1 += ks0 + 5u;
#undef TF_R
    uint32_t bits = second ? x1 : x0;
    return __uint_as_float((bits >> 9) | 0x3f800000u) - 1.0f;
}

__device__ __forceinline__ float gumbel_from_u(float u) {
    return -logf(-logf(u + 1e-10f) + 1e-10f);
}

// ---------------- block reduction helper (256 threads = 4 waves) ----------------
__device__ __forceinline__ float blockReduce(float v, float* red, bool ismax) {
    #pragma unroll
    for (int o = 32; o > 0; o >>= 1) {
        float t = __shfl_down(v, o);
        v = ismax ? fmaxf(v, t) : v + t;
    }
    __syncthreads();
    if ((threadIdx.x & 63) == 0) red[threadIdx.x >> 6] = v;
    __syncthreads();
    return ismax ? fmaxf(fmaxf(red[0], red[1]), fmaxf(red[2], red[3]))
                 : (red[0] + red[1] + red[2] + red[3]);
}

// ---------------- K1: codebook row norms ----------------
__global__ __launch_bounds__(64) void k_cnorm(const float* __restrict__ cb,
                                              float* __restrict__ cnorm) {
    const int k = blockIdx.x;
    const int lane = threadIdx.x;
    const float* row = cb + (size_t)k * DDIM;
    float4 a = *(const float4*)(row + lane * 4);
    float4 b = *(const float4*)(row + 256 + lane * 4);
    float s = a.x*a.x + a.y*a.y + a.z*a.z + a.w*a.w
            + b.x*b.x + b.y*b.y + b.z*b.z + b.w*b.w;
    #pragma unroll
    for (int o = 32; o > 0; o >>= 1) s += __shfl_down(s, o);
    if (lane == 0) cnorm[k] = s;
}

// ---------------- K2: GEMM1 (MFMA, bf16 3-term split) ----------------
// logit' = w*(2*z.c - |c|^2).  C = z[4096x512] * cb^T (gemm_bt pattern).
// 128x128 tile, BK=32, 4 waves (2x2), each wave 64x64 (4x4 16x16 tiles).
#define LD1 56   // LDS row stride in bf16 elems (112B: 16B-aligned, 2-way bank spread)
__global__ __launch_bounds__(256) void k_gemm1(const float* __restrict__ z,
                                               const float* __restrict__ cb,
                                               const float* __restrict__ cnorm,
                                               const float* __restrict__ var_q,
                                               float* __restrict__ logit) {
    __shared__ __align__(16) unsigned short AH[128 * LD1];
    __shared__ __align__(16) unsigned short AL[128 * LD1];
    __shared__ __align__(16) unsigned short BH[128 * LD1];
    __shared__ __align__(16) unsigned short BL[128 * LD1];
    const int t    = threadIdx.x;
    const int m0   = blockIdx.y * 128;
    const int n0   = blockIdx.x * 128;
    const int w    = t >> 6;
    const int lane = t & 63;
    const int wm   = (w >> 1) * 64;
    const int wn   = (w & 1) * 64;
    const int lrow = lane & 15;   // frag row/col within 16
    const int lq   = lane >> 4;   // quad 0..3
    const int srow = t >> 3;      // staging row 0..31 (+32i)
    const int skq  = (t & 7) * 4; // staging k-offset

    f32x4 acc[4][4];
    #pragma unroll
    for (int i = 0; i < 4; ++i)
        #pragma unroll
        for (int j = 0; j < 4; ++j)
            acc[i][j] = (f32x4){0.f, 0.f, 0.f, 0.f};

    for (int kt = 0; kt < DDIM; kt += 32) {
        __syncthreads();
        #pragma unroll
        for (int i = 0; i < 4; ++i) {
            const int r = srow + i * 32;
            float4 av = *(const float4*)(z  + (size_t)(m0 + r) * DDIM + kt + skq);
            float4 bv = *(const float4*)(cb + (size_t)(n0 + r) * DDIM + kt + skq);
            float a4[4] = {av.x, av.y, av.z, av.w};
            float b4[4] = {bv.x, bv.y, bv.z, bv.w};
            ushort4 ah, al, bh, bl;
            unsigned short* ahp = (unsigned short*)&ah;
            unsigned short* alp = (unsigned short*)&al;
            unsigned short* bhp = (unsigned short*)&bh;
            unsigned short* blp = (unsigned short*)&bl;
            #pragma unroll
            for (int e = 0; e < 4; ++e) {
                unsigned short h = f2bf(a4[e]);
                float hf = __uint_as_float((uint32_t)h << 16);
                ahp[e] = h; alp[e] = f2bf(a4[e] - hf);
                h = f2bf(b4[e]);
                hf = __uint_as_float((uint32_t)h << 16);
                bhp[e] = h; blp[e] = f2bf(b4[e] - hf);
            }
            *(ushort4*)&AH[r * LD1 + skq] = ah;
            *(ushort4*)&AL[r * LD1 + skq] = al;
            *(ushort4*)&BH[r * LD1 + skq] = bh;
            *(ushort4*)&BL[r * LD1 + skq] = bl;
        }
        __syncthreads();

        short8 ah[4], al[4], bh[4], bl[4];
        #pragma unroll
        for (int mt = 0; mt < 4; ++mt) {
            const int row = wm + mt * 16 + lrow;
            ah[mt] = *(const short8*)&AH[row * LD1 + lq * 8];
            al[mt] = *(const short8*)&AL[row * LD1 + lq * 8];
        }
        #pragma unroll
        for (int nt = 0; nt < 4; ++nt) {
            const int row = wn + nt * 16 + lrow;
            bh[nt] = *(const short8*)&BH[row * LD1 + lq * 8];
            bl[nt] = *(const short8*)&BL[row * LD1 + lq * 8];
        }
        #pragma unroll
        for (int mt = 0; mt < 4; ++mt)
            #pragma unroll
            for (int nt = 0; nt < 4; ++nt) {
                acc[mt][nt] = __builtin_amdgcn_mfma_f32_16x16x32_bf16(ah[mt], bh[nt], acc[mt][nt], 0, 0, 0);
                acc[mt][nt] = __builtin_amdgcn_mfma_f32_16x16x32_bf16(ah[mt], bl[nt], acc[mt][nt], 0, 0, 0);
                acc[mt][nt] = __builtin_amdgcn_mfma_f32_16x16x32_bf16(al[mt], bh[nt], acc[mt][nt], 0, 0, 0);
            }
    }

    const float wq = 0.5f / fmaxf(var_q[0], 1e-10f);
    #pragma unroll
    for (int nt = 0; nt < 4; ++nt) {
        const int gcol = n0 + wn + nt * 16 + lrow;
        const float cn = cnorm[gcol];
        #pragma unroll
        for (int mt = 0; mt < 4; ++mt) {
            #pragma unroll
            for (int r = 0; r < 4; ++r) {
                const int grow = m0 + wm + mt * 16 + lq * 4 + r;
                logit[(size_t)grow * KCODES + gcol] = wq * (2.0f * acc[mt][nt][r] - cn);
            }
        }
    }
}

// ---------------- K3: per-row stats (softmax + gumbel-softmax) ----------------
__global__ __launch_bounds__(256) void k_stats(const float* __restrict__ logit,
                                               float* __restrict__ rowm1,
                                               float* __restrict__ rows1,
                                               float* __restrict__ rowm2,
                                               float* __restrict__ rows2,
                                               float* __restrict__ acc) {
    __shared__ float sy[KCODES];
    __shared__ float red[4];
    const int n = blockIdx.x;
    const int t = threadIdx.x;
    const float* lrow = logit + (size_t)n * KCODES;
    float m1 = -3.0e38f, m2 = -3.0e38f;
    for (int c = t * 4; c < KCODES; c += 1024) {
        float4 v = *(const float4*)(lrow + c);
        float l4[4] = {v.x, v.y, v.z, v.w};
        float y4[4];
        #pragma unroll
        for (int i = 0; i < 4; ++i) {
            float u = jax_uniform((uint32_t)(n * KCODES + c + i));
            float g = gumbel_from_u(u);
            y4[i] = (l4[i] + g) * 2.0f;
            m1 = fmaxf(m1, l4[i]);
            m2 = fmaxf(m2, y4[i]);
        }
        *(float4*)&sy[c] = make_float4(y4[0], y4[1], y4[2], y4[3]);
    }
    m1 = blockReduce(m1, red, true);
    m2 = blockReduce(m2, red, true);
    float s1 = 0.0f, t1 = 0.0f, s2 = 0.0f;
    for (int c = t * 4; c < KCODES; c += 1024) {
        float4 v  = *(const float4*)(lrow + c);
        float4 yv = *(const float4*)&sy[c];
        float l4[4] = {v.x, v.y, v.z, v.w};
        float y4[4] = {yv.x, yv.y, yv.z, yv.w};
        #pragma unroll
        for (int i = 0; i < 4; ++i) {
            float x = l4[i] - m1;
            float e = expf(x);
            s1 += e;
            t1 += e * x;
            s2 += expf(y4[i] - m2);
        }
    }
    s1 = blockReduce(s1, red, false);
    t1 = blockReduce(t1, red, false);
    s2 = blockReduce(s2, red, false);
    if (t == 0) {
        rowm1[n] = m1; rows1[n] = s1;
        rowm2[n] = m2; rows2[n] = s2;
        atomicAdd(acc + 0, t1 / s1 - logf(s1));
    }
}

// ---------------- K4: column sums of probs (for perplexity) ----------------
__global__ __launch_bounds__(256) void k_colsum(const float* __restrict__ logit,
                                                const float* __restrict__ rowm1,
                                                const float* __restrict__ rows1,
                                                float* __restrict__ colsum) {
    __shared__ float sm[256], ss[256];
    const int t  = threadIdx.x;
    const int c0 = blockIdx.x * 512;
    const int r0 = blockIdx.y * 256;
    sm[t] = rowm1[r0 + t];
    ss[t] = 1.0f / rows1[r0 + t];
    __syncthreads();
    float a0 = 0.0f, a1 = 0.0f;
    for (int r = 0; r < 256; ++r) {
        float2 v = *(const float2*)(logit + (size_t)(r0 + r) * KCODES + c0 + 2 * t);
        float m = sm[r], is = ss[r];
        a0 += expf(v.x - m) * is;
        a1 += expf(v.y - m) * is;
    }
    atomicAdd(&colsum[c0 + 2 * t],     a0);
    atomicAdd(&colsum[c0 + 2 * t + 1], a1);
}

// ---------------- K5: encodings (in-place fp32 over logit) ----------------
__global__ __launch_bounds__(256) void k_enc(float* __restrict__ logit,
                                             const float* __restrict__ rowm2,
                                             const float* __restrict__ rows2) {
    const int idx4 = (blockIdx.x * 256 + threadIdx.x) * 4;
    const int n = idx4 >> 13;
    const float m2  = rowm2[n];
    const float inv = 1.0f / rows2[n];
    float4 v = *(float4*)(logit + idx4);
    float l4[4] = {v.x, v.y, v.z, v.w};
    float o4[4];
    #pragma unroll
    for (int i = 0; i < 4; ++i) {
        float u = jax_uniform((uint32_t)(idx4 + i));
        float g = gumbel_from_u(u);
        float y = (l4[i] + g) * 2.0f;
        o4[i] = expf(y - m2) * inv;
    }
    *(float4*)(logit + idx4) = make_float4(o4[0], o4[1], o4[2], o4[3]);
}

// ---------------- K6: GEMM2 (MFMA bf16) z_hat = enc @ cb + fused loss ----------------
// C[4096x512] = enc[4096x8192] @ cb[8192x512].  128x64 tile, BK=64.
// A staged via LDS (fp32->bf16 cvt); B frags loaded directly from global cb.
#define LD2 72   // LDS row stride in bf16 (144B: 16B-aligned, good bank spread)
__global__ __launch_bounds__(256) void k_gemm2(const float* __restrict__ enc,
                                               const float* __restrict__ cb,
                                               const float* __restrict__ z,
                                               float* __restrict__ out,
                                               float* __restrict__ accg) {
    __shared__ __align__(16) unsigned short AS[128 * LD2];
    __shared__ float red[4];
    const int t    = threadIdx.x;
    const int m0   = blockIdx.y * 128;
    const int n0   = blockIdx.x * 64;
    const int w    = t >> 6;
    const int lane = t & 63;
    const int wm   = (w >> 1) * 64;
    const int wn   = (w & 1) * 32;
    const int lrow = lane & 15;
    const int lq   = lane >> 4;

    f32x4 acc[4][2];
    #pragma unroll
    for (int i = 0; i < 4; ++i) {
        acc[i][0] = (f32x4){0.f, 0.f, 0.f, 0.f};
        acc[i][1] = (f32x4){0.f, 0.f, 0.f, 0.f};
    }

    for (int kt = 0; kt < KCODES; kt += 64) {
        __syncthreads();
        // A staging: 128 rows x 64 k fp32 -> bf16 LDS; 8 float4/thread
        #pragma unroll
        for (int j = 0; j < 8; ++j) {
            const int row = (t >> 4) + j * 16;
            const int q   = t & 15;
            float4 v = *(const float4*)(enc + (size_t)(m0 + row) * KCODES + kt + q * 4);
            ushort4 hv;
            unsigned short* hp = (unsigned short*)&hv;
            hp[0] = f2bf(v.x); hp[1] = f2bf(v.y); hp[2] = f2bf(v.z); hp[3] = f2bf(v.w);
            *(ushort4*)&AS[row * LD2 + q * 4] = hv;
        }
        __syncthreads();

        // B fragments direct from global fp32 cb[k][n]
        short8 bfr[2][2];
        #pragma unroll
        for (int chunk = 0; chunk < 2; ++chunk)
            #pragma unroll
            for (int nt = 0; nt < 2; ++nt) {
                const int n  = n0 + wn + nt * 16 + lrow;
                const int kb = kt + chunk * 32 + lq * 8;
                short8 bv;
                #pragma unroll
                for (int j = 0; j < 8; ++j) {
                    float f = cb[(size_t)(kb + j) * DDIM + n];
                    bv[j] = (short)f2bf(f);
                }
                bfr[chunk][nt] = bv;
            }

        #pragma unroll
        for (int chunk = 0; chunk < 2; ++chunk) {
            short8 af[4];
            #pragma unroll
            for (int mt = 0; mt < 4; ++mt)
                af[mt] = *(const short8*)&AS[(wm + mt * 16 + lrow) * LD2 + chunk * 32 + lq * 8];
            #pragma unroll
            for (int mt = 0; mt < 4; ++mt)
                #pragma unroll
                for (int nt = 0; nt < 2; ++nt)
                    acc[mt][nt] = __builtin_amdgcn_mfma_f32_16x16x32_bf16(af[mt], bfr[chunk][nt], acc[mt][nt], 0, 0, 0);
        }
    }

    // epilogue: store z_hat + fused (z - z_hat)^2 partial
    float part = 0.0f;
    #pragma unroll
    for (int mt = 0; mt < 4; ++mt)
        #pragma unroll
        for (int nt = 0; nt < 2; ++nt)
            #pragma unroll
            for (int r = 0; r < 4; ++r) {
                const int grow = m0 + wm + mt * 16 + lq * 4 + r;
                const int gcol = n0 + wn + nt * 16 + lrow;
                const float o = acc[mt][nt][r];
                out[(size_t)grow * DDIM + gcol] = o;
                const float d = z[(size_t)grow * DDIM + gcol] - o;
                part += d * d;
            }
    #pragma unroll
    for (int o = 32; o > 0; o >>= 1) part += __shfl_down(part, o);
    if ((t & 63) == 0) red[t >> 6] = part;
    __syncthreads();
    if (t == 0) atomicAdd(accg + 1, red[0] + red[1] + red[2] + red[3]);
}

// ---------------- K7: finalize loss + perplexity ----------------
__global__ __launch_bounds__(256) void k_final(const float* __restrict__ colsum,
                                               const float* __restrict__ acc,
                                               const float* __restrict__ var_q,
                                               float* __restrict__ out) {
    __shared__ float red[4];
    const int t = threadIdx.x;
    float s = 0.0f;
    for (int k = t; k < KCODES; k += 256) {
        float a = colsum[k] * INV_N;
        s += a * logf(a + 1e-7f);
    }
    s = blockReduce(s, red, false);
    if (t == 0) {
        float w = 0.5f / fmaxf(var_q[0], 1e-10f);
        float loss = acc[0] / BS_F + acc[1] * w / BS_F;
        out[(size_t)N_ROWS * DDIM]     = loss;
        out[(size_t)N_ROWS * DDIM + 1] = expf(-s);
    }
}

// ---------------- launch ----------------
extern "C" void kernel_launch(void* const* d_in, const int* in_sizes, int n_in,
                              void* d_out, int out_size, void* d_ws, size_t ws_size,
                              hipStream_t stream) {
    const float* z     = (const float*)d_in[0];
    const float* var_q = (const float*)d_in[1];
    const float* cb    = (const float*)d_in[2];
    float* out = (float*)d_out;
    float* ws  = (float*)d_ws;
    if (ws_size < (size_t)WS_FLOATS * sizeof(float)) return;

    float* logit  = ws + OFF_LOGIT;
    float* cnorm  = ws + OFF_CNORM;
    float* rowm1  = ws + OFF_ROWM1;
    float* rows1  = ws + OFF_ROWS1;
    float* rowm2  = ws + OFF_ROWM2;
    float* rows2  = ws + OFF_ROWS2;
    float* colsum = ws + OFF_COLSUM;
    float* accp   = ws + OFF_ACC;

    hipMemsetAsync(colsum, 0, (KCODES + 2) * sizeof(float), stream);

    k_cnorm <<<KCODES, 64, 0, stream>>>(cb, cnorm);
    k_gemm1 <<<dim3(KCODES / 128, N_ROWS / 128), 256, 0, stream>>>(z, cb, cnorm, var_q, logit);
    k_stats <<<N_ROWS, 256, 0, stream>>>(logit, rowm1, rows1, rowm2, rows2, accp);
    k_colsum<<<dim3(KCODES / 512, N_ROWS / 256), 256, 0, stream>>>(logit, rowm1, rows1, colsum);
    k_enc   <<<NK / 1024, 256, 0, stream>>>(logit, rowm2, rows2);
    k_gemm2 <<<dim3(DDIM / 64, N_ROWS / 128), 256, 0, stream>>>(logit, cb, z, out, accp);
    k_final <<<1, 256, 0, stream>>>(colsum, accp, var_q, out);
}

// Round 3
// 594.492 us; speedup vs baseline: 2.1184x; 1.1405x over previous
//
#include <hip/hip_runtime.h>
#include <stdint.h>

// ---------------- problem constants ----------------
#define N_ROWS 4096      // bs*seq = 8*512
#define DDIM   512
#define KCODES 8192
#define NK     (N_ROWS * KCODES)   // 33,554,432
#define HALF_NK 16777216u
#define BS_F   8.0f
#define INV_N  (1.0f / 4096.0f)

// ---------------- ws layout (float offsets) ----------------
// logit region (NK floats) also hosts the in-place bf16 encodings:
// row n's bf16 encodings live in the first 16KB of row n's 32KB slot.
#define OFF_LOGIT   0
#define OFF_CNORM   (NK)
#define OFF_ROWM1   (OFF_CNORM + KCODES)
#define OFF_ROWS1   (OFF_ROWM1 + N_ROWS)
#define OFF_ROWM2   (OFF_ROWS1 + N_ROWS)
#define OFF_ROWS2   (OFF_ROWM2 + N_ROWS)
#define OFF_COLSUM  (OFF_ROWS2 + N_ROWS)
#define OFF_ACC     (OFF_COLSUM + KCODES)   // [0]=sum p*logp, [1]=sum (z-zhat)^2
#define OFF_ZH      (OFF_ACC + 4)                    // bf16 z hi  [4096*512]
#define OFF_ZL      (OFF_ZH + (N_ROWS*DDIM/2))       // bf16 z lo
#define OFF_CBH     (OFF_ZL + (N_ROWS*DDIM/2))       // bf16 cb hi [8192*512]
#define OFF_CBL     (OFF_CBH + (KCODES*DDIM/2))      // bf16 cb lo
#define OFF_CBT     (OFF_CBL + (KCODES*DDIM/2))      // bf16 cb^T  [512*8192]
#define WS_FLOATS   (OFF_CBT + (DDIM*KCODES/2))      // ~41.9M floats ~168MB

typedef __attribute__((ext_vector_type(8))) short short8;
typedef __attribute__((ext_vector_type(4))) float f32x4;

__device__ __forceinline__ unsigned short f2bf(float x) {
    uint32_t u = __float_as_uint(x);
    u += 0x7fffu + ((u >> 16) & 1u);
    return (unsigned short)(u >> 16);
}

// ---------------- JAX threefry2x32-20, key(42) = (0,42) ----------------
__device__ __forceinline__ uint32_t rotl32(uint32_t x, int r) {
    return (x << r) | (x >> (32 - r));
}

__device__ __forceinline__ float jax_uniform(uint32_t j) {
    uint32_t c0, c1;
    bool second;
    if (j < HALF_NK) { c0 = j; c1 = j + HALF_NK; second = false; }
    else             { c0 = j - HALF_NK; c1 = j; second = true;  }
    const uint32_t ks0 = 0u, ks1 = 42u, ks2 = 0x1BD11BDAu ^ 0u ^ 42u;
    uint32_t x0 = c0 + ks0;
    uint32_t x1 = c1 + ks1;
#define TF_R(r) { x0 += x1; x1 = rotl32(x1, r); x1 ^= x0; }
    TF_R(13) TF_R(15) TF_R(26) TF_R(6)
    x0 += ks1; x1 += ks2 + 1u;
    TF_R(17) TF_R(29) TF_R(16) TF_R(24)
    x0 += ks2; x1 += ks0 + 2u;
    TF_R(13) TF_R(15) TF_R(26) TF_R(6)
    x0 += ks0; x1 += ks1 + 3u;
    TF_R(17) TF_R(29) TF_R(16) TF_R(24)
    x0 += ks1; x1 += ks2 + 4u;
    TF_R(13) TF_R(15) TF_R(26) TF_R(6)
    x0 += ks2; x1 += ks0 + 5u;
#undef TF_R
    uint32_t bits = second ? x1 : x0;
    return __uint_as_float((bits >> 9) | 0x3f800000u) - 1.0f;
}

__device__ __forceinline__ float gumbel_from_u(float u) {
    return -logf(-logf(u + 1e-10f) + 1e-10f);
}

__device__ __forceinline__ float blockReduce(float v, float* red, bool ismax) {
    #pragma unroll
    for (int o = 32; o > 0; o >>= 1) {
        float t = __shfl_down(v, o);
        v = ismax ? fmaxf(v, t) : v + t;
    }
    __syncthreads();
    if ((threadIdx.x & 63) == 0) red[threadIdx.x >> 6] = v;
    __syncthreads();
    return ismax ? fmaxf(fmaxf(red[0], red[1]), fmaxf(red[2], red[3]))
                 : (red[0] + red[1] + red[2] + red[3]);
}

// ---------------- P1: split z -> bf16 hi/lo ----------------
__global__ __launch_bounds__(256) void k_split(const float* __restrict__ src,
                                               unsigned short* __restrict__ hi,
                                               unsigned short* __restrict__ lo) {
    const size_t idx = ((size_t)blockIdx.x * 256 + threadIdx.x) * 8;
    float4 a = *(const float4*)(src + idx);
    float4 b = *(const float4*)(src + idx + 4);
    float f[8] = {a.x, a.y, a.z, a.w, b.x, b.y, b.z, b.w};
    unsigned short h8[8], l8[8];
    #pragma unroll
    for (int e = 0; e < 8; ++e) {
        unsigned short h = f2bf(f[e]);
        float hf = __uint_as_float((uint32_t)h << 16);
        h8[e] = h;
        l8[e] = f2bf(f[e] - hf);
    }
    *(short8*)(hi + idx) = *(short8*)h8;
    *(short8*)(lo + idx) = *(short8*)l8;
}

// ---------------- P2: codebook row norms ----------------
__global__ __launch_bounds__(64) void k_cnorm(const float* __restrict__ cb,
                                              float* __restrict__ cnorm) {
    const int k = blockIdx.x;
    const int lane = threadIdx.x;
    const float* row = cb + (size_t)k * DDIM;
    float4 a = *(const float4*)(row + lane * 4);
    float4 b = *(const float4*)(row + 256 + lane * 4);
    float s = a.x*a.x + a.y*a.y + a.z*a.z + a.w*a.w
            + b.x*b.x + b.y*b.y + b.z*b.z + b.w*b.w;
    #pragma unroll
    for (int o = 32; o > 0; o >>= 1) s += __shfl_down(s, o);
    if (lane == 0) cnorm[k] = s;
}

// ---------------- P3: cb[k][d] -> cbT bf16 [d][k] ----------------
__global__ __launch_bounds__(256) void k_trans(const float* __restrict__ cb,
                                               unsigned short* __restrict__ cbT) {
    __shared__ unsigned short TT[64][65];
    const int t  = threadIdx.x;
    const int k0 = blockIdx.x * 64;
    const int d0 = blockIdx.y * 64;
    #pragma unroll
    for (int j = 0; j < 4; ++j) {
        const int unit = t + j * 256;
        const int r = unit >> 4;
        const int s = unit & 15;
        float4 v = *(const float4*)(cb + (size_t)(k0 + r) * DDIM + d0 + s * 4);
        TT[r][s*4+0] = f2bf(v.x); TT[r][s*4+1] = f2bf(v.y);
        TT[r][s*4+2] = f2bf(v.z); TT[r][s*4+3] = f2bf(v.w);
    }
    __syncthreads();
    #pragma unroll
    for (int j = 0; j < 2; ++j) {
        const int unit = t + j * 256;
        const int dr = unit >> 3;
        const int ks = (unit & 7) * 8;
        unsigned short o8[8];
        #pragma unroll
        for (int i = 0; i < 8; ++i) o8[i] = TT[ks + i][dr];
        *(short8*)(cbT + (size_t)(d0 + dr) * KCODES + k0 + ks) = *(short8*)o8;
    }
}

// ---------------- K2: GEMM1 (MFMA, pre-split bf16 3-term) ----------------
// logit' = w*(2*z.c^T - |c|^2).  128x128 tile, BK=32, 4 waves 2x2.
#define BK1 32
__global__ __launch_bounds__(256) void k_gemm1(const unsigned short* __restrict__ zh,
                                               const unsigned short* __restrict__ zl,
                                               const unsigned short* __restrict__ cbh,
                                               const unsigned short* __restrict__ cbl,
                                               const float* __restrict__ cnorm,
                                               const float* __restrict__ var_q,
                                               float* __restrict__ logit) {
    __shared__ __align__(16) unsigned short AH[128 * BK1];
    __shared__ __align__(16) unsigned short AL[128 * BK1];
    __shared__ __align__(16) unsigned short BH[128 * BK1];
    __shared__ __align__(16) unsigned short BL[128 * BK1];
    const int t    = threadIdx.x;
    const int n0   = blockIdx.x * 128;
    const int m0   = blockIdx.y * 128;
    const int w    = t >> 6;
    const int lane = t & 63;
    const int wm   = (w >> 1) * 64;
    const int wn   = (w & 1) * 64;
    const int lrow = lane & 15;
    const int lq   = lane >> 4;

    f32x4 acc[4][4];
    #pragma unroll
    for (int i = 0; i < 4; ++i)
        #pragma unroll
        for (int j = 0; j < 4; ++j)
            acc[i][j] = (f32x4){0.f, 0.f, 0.f, 0.f};

    for (int kt = 0; kt < DDIM; kt += BK1) {
        __syncthreads();
        #pragma unroll
        for (int j = 0; j < 2; ++j) {
            const int unit = t + j * 256;
            const int row  = unit >> 2;
            const int seg  = (unit & 3) * 8;
            const size_t ga = (size_t)(m0 + row) * DDIM + kt + seg;
            const size_t gb = (size_t)(n0 + row) * DDIM + kt + seg;
            *(short8*)&AH[row * BK1 + seg] = *(const short8*)(zh  + ga);
            *(short8*)&AL[row * BK1 + seg] = *(const short8*)(zl  + ga);
            *(short8*)&BH[row * BK1 + seg] = *(const short8*)(cbh + gb);
            *(short8*)&BL[row * BK1 + seg] = *(const short8*)(cbl + gb);
        }
        __syncthreads();

        short8 ah[4], al[4], bh[4], bl[4];
        #pragma unroll
        for (int mt = 0; mt < 4; ++mt) {
            const int row = wm + mt * 16 + lrow;
            ah[mt] = *(const short8*)&AH[row * BK1 + lq * 8];
            al[mt] = *(const short8*)&AL[row * BK1 + lq * 8];
        }
        #pragma unroll
        for (int nt = 0; nt < 4; ++nt) {
            const int row = wn + nt * 16 + lrow;
            bh[nt] = *(const short8*)&BH[row * BK1 + lq * 8];
            bl[nt] = *(const short8*)&BL[row * BK1 + lq * 8];
        }
        #pragma unroll
        for (int mt = 0; mt < 4; ++mt)
            #pragma unroll
            for (int nt = 0; nt < 4; ++nt) {
                acc[mt][nt] = __builtin_amdgcn_mfma_f32_16x16x32_bf16(ah[mt], bh[nt], acc[mt][nt], 0, 0, 0);
                acc[mt][nt] = __builtin_amdgcn_mfma_f32_16x16x32_bf16(ah[mt], bl[nt], acc[mt][nt], 0, 0, 0);
                acc[mt][nt] = __builtin_amdgcn_mfma_f32_16x16x32_bf16(al[mt], bh[nt], acc[mt][nt], 0, 0, 0);
            }
    }

    const float wq = 0.5f / fmaxf(var_q[0], 1e-10f);
    #pragma unroll
    for (int nt = 0; nt < 4; ++nt) {
        const int gcol = n0 + wn + nt * 16 + lrow;
        const float cn = cnorm[gcol];
        #pragma unroll
        for (int mt = 0; mt < 4; ++mt) {
            #pragma unroll
            for (int r = 0; r < 4; ++r) {
                const int grow = m0 + wm + mt * 16 + lq * 4 + r;
                logit[(size_t)grow * KCODES + gcol] = wq * (2.0f * acc[mt][nt][r] - cn);
            }
        }
    }
}

// ---------------- K3: per-row stats ----------------
__global__ __launch_bounds__(256) void k_stats(const float* __restrict__ logit,
                                               float* __restrict__ rowm1,
                                               float* __restrict__ rows1,
                                               float* __restrict__ rowm2,
                                               float* __restrict__ rows2,
                                               float* __restrict__ acc) {
    __shared__ float sy[KCODES];
    __shared__ float red[4];
    const int n = blockIdx.x;
    const int t = threadIdx.x;
    const float* lrow = logit + (size_t)n * KCODES;
    float m1 = -3.0e38f, m2 = -3.0e38f;
    for (int c = t * 4; c < KCODES; c += 1024) {
        float4 v = *(const float4*)(lrow + c);
        float l4[4] = {v.x, v.y, v.z, v.w};
        float y4[4];
        #pragma unroll
        for (int i = 0; i < 4; ++i) {
            float u = jax_uniform((uint32_t)(n * KCODES + c + i));
            float g = gumbel_from_u(u);
            y4[i] = (l4[i] + g) * 2.0f;
            m1 = fmaxf(m1, l4[i]);
            m2 = fmaxf(m2, y4[i]);
        }
        *(float4*)&sy[c] = make_float4(y4[0], y4[1], y4[2], y4[3]);
    }
    m1 = blockReduce(m1, red, true);
    m2 = blockReduce(m2, red, true);
    float s1 = 0.0f, t1 = 0.0f, s2 = 0.0f;
    for (int c = t * 4; c < KCODES; c += 1024) {
        float4 v  = *(const float4*)(lrow + c);
        float4 yv = *(const float4*)&sy[c];
        float l4[4] = {v.x, v.y, v.z, v.w};
        float y4[4] = {yv.x, yv.y, yv.z, yv.w};
        #pragma unroll
        for (int i = 0; i < 4; ++i) {
            float x = l4[i] - m1;
            float e = expf(x);
            s1 += e;
            t1 += e * x;
            s2 += expf(y4[i] - m2);
        }
    }
    s1 = blockReduce(s1, red, false);
    t1 = blockReduce(t1, red, false);
    s2 = blockReduce(s2, red, false);
    if (t == 0) {
        rowm1[n] = m1; rows1[n] = s1;
        rowm2[n] = m2; rows2[n] = s2;
        atomicAdd(acc + 0, t1 / s1 - logf(s1));
    }
}

// ---------------- K4: column sums of probs ----------------
__global__ __launch_bounds__(256) void k_colsum(const float* __restrict__ logit,
                                                const float* __restrict__ rowm1,
                                                const float* __restrict__ rows1,
                                                float* __restrict__ colsum) {
    __shared__ float sm[256], ss[256];
    const int t  = threadIdx.x;
    const int c0 = blockIdx.x * 512;
    const int r0 = blockIdx.y * 256;
    sm[t] = rowm1[r0 + t];
    ss[t] = 1.0f / rows1[r0 + t];
    __syncthreads();
    float a0 = 0.0f, a1 = 0.0f;
    for (int r = 0; r < 256; ++r) {
        float2 v = *(const float2*)(logit + (size_t)(r0 + r) * KCODES + c0 + 2 * t);
        float m = sm[r], is = ss[r];
        a0 += expf(v.x - m) * is;
        a1 += expf(v.y - m) * is;
    }
    atomicAdd(&colsum[c0 + 2 * t],     a0);
    atomicAdd(&colsum[c0 + 2 * t + 1], a1);
}

// ---------------- K5: encodings -> bf16, in-place in row slot ----------------
// One block per row. Reads the row's 8192 fp32 logits into registers,
// syncs, then writes 8192 bf16 encodings into the first 16KB of the slot.
__global__ __launch_bounds__(256) void k_enc(float* __restrict__ logit,
                                             const float* __restrict__ rowm2,
                                             const float* __restrict__ rows2) {
    const int n = blockIdx.x;
    const int t = threadIdx.x;
    const float m2  = rowm2[n];
    const float inv = 1.0f / rows2[n];
    const size_t base = (size_t)n * KCODES;
    float4 v[8];
    #pragma unroll
    for (int j = 0; j < 8; ++j)
        v[j] = *(const float4*)(logit + base + t * 32 + j * 4);
    unsigned short o[32];
    #pragma unroll
    for (int j = 0; j < 8; ++j) {
        float l4[4] = {v[j].x, v[j].y, v[j].z, v[j].w};
        #pragma unroll
        for (int i = 0; i < 4; ++i) {
            const uint32_t idx = (uint32_t)(n * KCODES + t * 32 + j * 4 + i);
            float u = jax_uniform(idx);
            float g = gumbel_from_u(u);
            float y = (l4[i] + g) * 2.0f;
            o[j * 4 + i] = f2bf(expf(y - m2) * inv);
        }
    }
    __syncthreads();   // all reads of this row done before overwriting
    unsigned short* dst = (unsigned short*)logit + (size_t)n * (2 * KCODES) + t * 32;
    #pragma unroll
    for (int j = 0; j < 4; ++j)
        *(short8*)(dst + j * 8) = *(short8*)&o[j * 8];
}

// ---------------- K6: GEMM2 z_hat = enc16 @ cbT^T (K-split, atomic out) ----
// enc16: bf16, row n at ushort-offset n*16384, 8192 valid k.
// cbT:   bf16 [512][8192].  Tile 64 rows x 256 cols, 4 waves (1x4), BK=64.
#define BK2 64
__global__ __launch_bounds__(256) void k_gemm2(const unsigned short* __restrict__ enc16,
                                               const unsigned short* __restrict__ cbT,
                                               float* __restrict__ out) {
    __shared__ __align__(16) unsigned short AS[64 * BK2];
    const int t    = threadIdx.x;
    const int n0   = blockIdx.x * 256;
    const int m0   = blockIdx.y * 64;
    const int kz0  = blockIdx.z * (KCODES / 4);
    const int w    = t >> 6;
    const int lane = t & 63;
    const int wn   = w * 64;
    const int lrow = lane & 15;
    const int lq   = lane >> 4;

    f32x4 acc[4][4];
    #pragma unroll
    for (int i = 0; i < 4; ++i)
        #pragma unroll
        for (int j = 0; j < 4; ++j)
            acc[i][j] = (f32x4){0.f, 0.f, 0.f, 0.f};

    for (int kt = kz0; kt < kz0 + KCODES / 4; kt += BK2) {
        __syncthreads();
        #pragma unroll
        for (int j = 0; j < 2; ++j) {
            const int unit = t + j * 256;
            const int row  = unit >> 3;
            const int seg  = (unit & 7) * 8;
            *(short8*)&AS[row * BK2 + seg] =
                *(const short8*)(enc16 + (size_t)(m0 + row) * (2 * KCODES) + kt + seg);
        }
        __syncthreads();
        #pragma unroll
        for (int chunk = 0; chunk < 2; ++chunk) {
            short8 af[4];
            #pragma unroll
            for (int mt = 0; mt < 4; ++mt)
                af[mt] = *(const short8*)&AS[(mt * 16 + lrow) * BK2 + chunk * 32 + lq * 8];
            #pragma unroll
            for (int nt = 0; nt < 4; ++nt) {
                const short8 bf = *(const short8*)(cbT
                    + (size_t)(n0 + wn + nt * 16 + lrow) * KCODES + kt + chunk * 32 + lq * 8);
                #pragma unroll
                for (int mt = 0; mt < 4; ++mt)
                    acc[mt][nt] = __builtin_amdgcn_mfma_f32_16x16x32_bf16(af[mt], bf, acc[mt][nt], 0, 0, 0);
            }
        }
    }

    #pragma unroll
    for (int mt = 0; mt < 4; ++mt)
        #pragma unroll
        for (int nt = 0; nt < 4; ++nt)
            #pragma unroll
            for (int r = 0; r < 4; ++r) {
                const int grow = m0 + mt * 16 + lq * 4 + r;
                const int gcol = n0 + wn + nt * 16 + lrow;
                atomicAdd(&out[(size_t)grow * DDIM + gcol], acc[mt][nt][r]);
            }
}

// ---------------- K6b: fused continuous-KLD partial ----------------
__global__ __launch_bounds__(256) void k_loss2(const float* __restrict__ z,
                                               const float* __restrict__ out,
                                               float* __restrict__ acc) {
    __shared__ float red[4];
    const size_t idx = ((size_t)blockIdx.x * 256 + threadIdx.x) * 4;
    float4 zv = *(const float4*)(z + idx);
    float4 ov = *(const float4*)(out + idx);
    float dx = zv.x - ov.x, dy = zv.y - ov.y, dz = zv.z - ov.z, dw = zv.w - ov.w;
    float part = dx*dx + dy*dy + dz*dz + dw*dw;
    #pragma unroll
    for (int o = 32; o > 0; o >>= 1) part += __shfl_down(part, o);
    if ((threadIdx.x & 63) == 0) red[threadIdx.x >> 6] = part;
    __syncthreads();
    if (threadIdx.x == 0) atomicAdd(acc + 1, red[0] + red[1] + red[2] + red[3]);
}

// ---------------- K7: finalize ----------------
__global__ __launch_bounds__(256) void k_final(const float* __restrict__ colsum,
                                               const float* __restrict__ acc,
                                               const float* __restrict__ var_q,
                                               float* __restrict__ out) {
    __shared__ float red[4];
    const int t = threadIdx.x;
    float s = 0.0f;
    for (int k = t; k < KCODES; k += 256) {
        float a = colsum[k] * INV_N;
        s += a * logf(a + 1e-7f);
    }
    s = blockReduce(s, red, false);
    if (t == 0) {
        float w = 0.5f / fmaxf(var_q[0], 1e-10f);
        float loss = acc[0] / BS_F + acc[1] * w / BS_F;
        out[(size_t)N_ROWS * DDIM]     = loss;
        out[(size_t)N_ROWS * DDIM + 1] = expf(-s);
    }
}

// ---------------- launch ----------------
extern "C" void kernel_launch(void* const* d_in, const int* in_sizes, int n_in,
                              void* d_out, int out_size, void* d_ws, size_t ws_size,
                              hipStream_t stream) {
    const float* z     = (const float*)d_in[0];
    const float* var_q = (const float*)d_in[1];
    const float* cb    = (const float*)d_in[2];
    float* out = (float*)d_out;
    float* ws  = (float*)d_ws;
    if (ws_size < (size_t)WS_FLOATS * sizeof(float)) return;  // need ~168 MB

    float* logit  = ws + OFF_LOGIT;
    float* cnorm  = ws + OFF_CNORM;
    float* rowm1  = ws + OFF_ROWM1;
    float* rows1  = ws + OFF_ROWS1;
    float* rowm2  = ws + OFF_ROWM2;
    float* rows2  = ws + OFF_ROWS2;
    float* colsum = ws + OFF_COLSUM;
    float* accp   = ws + OFF_ACC;
    unsigned short* zh  = (unsigned short*)(ws + OFF_ZH);
    unsigned short* zl  = (unsigned short*)(ws + OFF_ZL);
    unsigned short* cbh = (unsigned short*)(ws + OFF_CBH);
    unsigned short* cbl = (unsigned short*)(ws + OFF_CBL);
    unsigned short* cbT = (unsigned short*)(ws + OFF_CBT);

    hipMemsetAsync(colsum, 0, (KCODES + 2) * sizeof(float), stream);
    hipMemsetAsync(out, 0, (size_t)N_ROWS * DDIM * sizeof(float), stream);

    k_split <<<N_ROWS * DDIM / 2048, 256, 0, stream>>>(z, zh, zl);
    k_split <<<KCODES * DDIM / 2048, 256, 0, stream>>>(cb, cbh, cbl);
    k_cnorm <<<KCODES, 64, 0, stream>>>(cb, cnorm);
    k_trans <<<dim3(KCODES / 64, DDIM / 64), 256, 0, stream>>>(cb, cbT);
    k_gemm1 <<<dim3(KCODES / 128, N_ROWS / 128), 256, 0, stream>>>(zh, zl, cbh, cbl, cnorm, var_q, logit);
    k_stats <<<N_ROWS, 256, 0, stream>>>(logit, rowm1, rows1, rowm2, rows2, accp);
    k_colsum<<<dim3(KCODES / 512, N_ROWS / 256), 256, 0, stream>>>(logit, rowm1, rows1, colsum);
    k_enc   <<<N_ROWS, 256, 0, stream>>>(logit, rowm2, rows2);
    k_gemm2 <<<dim3(DDIM / 256, N_ROWS / 64, 4), 256, 0, stream>>>((const unsigned short*)logit, cbT, out);
    k_loss2 <<<N_ROWS * DDIM / 1024, 256, 0, stream>>>(z, out, accp);
    k_final <<<1, 256, 0, stream>>>(colsum, accp, var_q, out);
}

// Round 4
// 453.670 us; speedup vs baseline: 2.7760x; 1.3104x over previous
//
#include <hip/hip_runtime.h>
#include <stdint.h>

// ---------------- problem constants ----------------
#define N_ROWS 4096      // bs*seq = 8*512
#define DDIM   512
#define KCODES 8192
#define NK     (N_ROWS * KCODES)   // 33,554,432
#define HALF_NK 16777216u
#define BS_F   8.0f
#define INV_N  (1.0f / 4096.0f)

// ---------------- ws layout (float offsets) ----------------
// logit region (NK floats) also hosts the in-place bf16 encodings:
// row n's bf16 encodings live in the first 16KB of row n's 32KB slot.
// zh/zl (2M floats) are DEAD after k_gemm1 -> reused as colsum partials [256][8192].
#define OFF_LOGIT   0
#define OFF_CNORM   (NK)
#define OFF_ACC     (OFF_CNORM + KCODES)   // [0]=sum p*logp, [1]=sum (z-zhat)^2, [2]=entropy
#define OFF_ZH      (OFF_ACC + 4)                    // bf16 z hi  [4096*512]
#define OFF_ZL      (OFF_ZH + (N_ROWS*DDIM/2))       // bf16 z lo
#define OFF_CBH     (OFF_ZL + (N_ROWS*DDIM/2))       // bf16 cb hi [8192*512]
#define OFF_CBL     (OFF_CBH + (KCODES*DDIM/2))      // bf16 cb lo
#define OFF_CBT     (OFF_CBL + (KCODES*DDIM/2))      // bf16 cb^T  [512*8192]
#define WS_FLOATS   (OFF_CBT + (DDIM*KCODES/2))      // ~168MB

typedef __attribute__((ext_vector_type(8))) short short8;
typedef __attribute__((ext_vector_type(4))) float f32x4;

__device__ __forceinline__ unsigned short f2bf(float x) {
    uint32_t u = __float_as_uint(x);
    u += 0x7fffu + ((u >> 16) & 1u);
    return (unsigned short)(u >> 16);
}

// ---------------- JAX threefry2x32-20, key(42) = (0,42) ----------------
__device__ __forceinline__ uint32_t rotl32(uint32_t x, int r) {
    return (x << r) | (x >> (32 - r));
}

// one threefry block -> BOTH outputs (counters c0,c1)
__device__ __forceinline__ void threefry2(uint32_t c0, uint32_t c1,
                                          uint32_t& o0, uint32_t& o1) {
    const uint32_t ks0 = 0u, ks1 = 42u, ks2 = 0x1BD11BDAu ^ 0u ^ 42u;
    uint32_t x0 = c0 + ks0;
    uint32_t x1 = c1 + ks1;
#define TF_R(r) { x0 += x1; x1 = rotl32(x1, r); x1 ^= x0; }
    TF_R(13) TF_R(15) TF_R(26) TF_R(6)
    x0 += ks1; x1 += ks2 + 1u;
    TF_R(17) TF_R(29) TF_R(16) TF_R(24)
    x0 += ks2; x1 += ks0 + 2u;
    TF_R(13) TF_R(15) TF_R(26) TF_R(6)
    x0 += ks0; x1 += ks1 + 3u;
    TF_R(17) TF_R(29) TF_R(16) TF_R(24)
    x0 += ks1; x1 += ks2 + 4u;
    TF_R(13) TF_R(15) TF_R(26) TF_R(6)
    x0 += ks2; x1 += ks0 + 5u;
#undef TF_R
    o0 = x0; o1 = x1;
}

__device__ __forceinline__ float u01(uint32_t bits) {
    return __uint_as_float((bits >> 9) | 0x3f800000u) - 1.0f;
}

__device__ __forceinline__ float gum(uint32_t bits) {
    float u = u01(bits);
    return -__logf(-__logf(u + 1e-10f) + 1e-10f);
}

// ---------------- block reduce helpers (256 threads = 4 waves) ----------------
__device__ __forceinline__ float blockReduce1(float v, float* red) {
    #pragma unroll
    for (int o = 32; o > 0; o >>= 1) v += __shfl_down(v, o);
    __syncthreads();
    if ((threadIdx.x & 63) == 0) red[threadIdx.x >> 6] = v;
    __syncthreads();
    return red[0] + red[1] + red[2] + red[3];
}

__device__ __forceinline__ void red2max(float& a, float& b, float* red) {
    #pragma unroll
    for (int o = 32; o > 0; o >>= 1) {
        a = fmaxf(a, __shfl_down(a, o));
        b = fmaxf(b, __shfl_down(b, o));
    }
    __syncthreads();
    if ((threadIdx.x & 63) == 0) {
        red[(threadIdx.x >> 6) * 2 + 0] = a;
        red[(threadIdx.x >> 6) * 2 + 1] = b;
    }
    __syncthreads();
    a = fmaxf(fmaxf(red[0], red[2]), fmaxf(red[4], red[6]));
    b = fmaxf(fmaxf(red[1], red[3]), fmaxf(red[5], red[7]));
}

__device__ __forceinline__ void red3sum(float& a, float& b, float& c, float* red) {
    #pragma unroll
    for (int o = 32; o > 0; o >>= 1) {
        a += __shfl_down(a, o);
        b += __shfl_down(b, o);
        c += __shfl_down(c, o);
    }
    __syncthreads();
    if ((threadIdx.x & 63) == 0) {
        red[(threadIdx.x >> 6) * 3 + 0] = a;
        red[(threadIdx.x >> 6) * 3 + 1] = b;
        red[(threadIdx.x >> 6) * 3 + 2] = c;
    }
    __syncthreads();
    a = red[0] + red[3] + red[6] + red[9];
    b = red[1] + red[4] + red[7] + red[10];
    c = red[2] + red[5] + red[8] + red[11];
}

// ---------------- P1: split -> bf16 hi/lo ----------------
__global__ __launch_bounds__(256) void k_split(const float* __restrict__ src,
                                               unsigned short* __restrict__ hi,
                                               unsigned short* __restrict__ lo) {
    const size_t idx = ((size_t)blockIdx.x * 256 + threadIdx.x) * 8;
    float4 a = *(const float4*)(src + idx);
    float4 b = *(const float4*)(src + idx + 4);
    float f[8] = {a.x, a.y, a.z, a.w, b.x, b.y, b.z, b.w};
    unsigned short h8[8], l8[8];
    #pragma unroll
    for (int e = 0; e < 8; ++e) {
        unsigned short h = f2bf(f[e]);
        float hf = __uint_as_float((uint32_t)h << 16);
        h8[e] = h;
        l8[e] = f2bf(f[e] - hf);
    }
    *(short8*)(hi + idx) = *(short8*)h8;
    *(short8*)(lo + idx) = *(short8*)l8;
}

// ---------------- P2: codebook row norms ----------------
__global__ __launch_bounds__(64) void k_cnorm(const float* __restrict__ cb,
                                              float* __restrict__ cnorm) {
    const int k = blockIdx.x;
    const int lane = threadIdx.x;
    const float* row = cb + (size_t)k * DDIM;
    float4 a = *(const float4*)(row + lane * 4);
    float4 b = *(const float4*)(row + 256 + lane * 4);
    float s = a.x*a.x + a.y*a.y + a.z*a.z + a.w*a.w
            + b.x*b.x + b.y*b.y + b.z*b.z + b.w*b.w;
    #pragma unroll
    for (int o = 32; o > 0; o >>= 1) s += __shfl_down(s, o);
    if (lane == 0) cnorm[k] = s;
}

// ---------------- P3: cb[k][d] -> cbT bf16 [d][k] ----------------
__global__ __launch_bounds__(256) void k_trans(const float* __restrict__ cb,
                                               unsigned short* __restrict__ cbT) {
    __shared__ unsigned short TT[64][65];
    const int t  = threadIdx.x;
    const int k0 = blockIdx.x * 64;
    const int d0 = blockIdx.y * 64;
    #pragma unroll
    for (int j = 0; j < 4; ++j) {
        const int unit = t + j * 256;
        const int r = unit >> 4;
        const int s = unit & 15;
        float4 v = *(const float4*)(cb + (size_t)(k0 + r) * DDIM + d0 + s * 4);
        TT[r][s*4+0] = f2bf(v.x); TT[r][s*4+1] = f2bf(v.y);
        TT[r][s*4+2] = f2bf(v.z); TT[r][s*4+3] = f2bf(v.w);
    }
    __syncthreads();
    #pragma unroll
    for (int j = 0; j < 2; ++j) {
        const int unit = t + j * 256;
        const int dr = unit >> 3;
        const int ks = (unit & 7) * 8;
        unsigned short o8[8];
        #pragma unroll
        for (int i = 0; i < 8; ++i) o8[i] = TT[ks + i][dr];
        *(short8*)(cbT + (size_t)(d0 + dr) * KCODES + k0 + ks) = *(short8*)o8;
    }
}

// ---------------- K2: GEMM1 (MFMA, pre-split bf16 3-term) ----------------
// 128x128 tile, BK=32.  LDS row stride 40 shorts (80B): 16B-granule stride 5,
// gcd(5,8)=1 -> conflict-free b128 reads/writes.
#define BK1 32
#define LD1 40
__global__ __launch_bounds__(256) void k_gemm1(const unsigned short* __restrict__ zh,
                                               const unsigned short* __restrict__ zl,
                                               const unsigned short* __restrict__ cbh,
                                               const unsigned short* __restrict__ cbl,
                                               const float* __restrict__ cnorm,
                                               const float* __restrict__ var_q,
                                               float* __restrict__ logit) {
    __shared__ __align__(16) unsigned short AH[128 * LD1];
    __shared__ __align__(16) unsigned short AL[128 * LD1];
    __shared__ __align__(16) unsigned short BH[128 * LD1];
    __shared__ __align__(16) unsigned short BL[128 * LD1];
    const int t    = threadIdx.x;
    const int n0   = blockIdx.x * 128;
    const int m0   = blockIdx.y * 128;
    const int w    = t >> 6;
    const int lane = t & 63;
    const int wm   = (w >> 1) * 64;
    const int wn   = (w & 1) * 64;
    const int lrow = lane & 15;
    const int lq   = lane >> 4;

    f32x4 acc[4][4];
    #pragma unroll
    for (int i = 0; i < 4; ++i)
        #pragma unroll
        for (int j = 0; j < 4; ++j)
            acc[i][j] = (f32x4){0.f, 0.f, 0.f, 0.f};

    for (int kt = 0; kt < DDIM; kt += BK1) {
        __syncthreads();
        #pragma unroll
        for (int j = 0; j < 2; ++j) {
            const int unit = t + j * 256;
            const int row  = unit >> 2;
            const int seg  = (unit & 3) * 8;
            const size_t ga = (size_t)(m0 + row) * DDIM + kt + seg;
            const size_t gb = (size_t)(n0 + row) * DDIM + kt + seg;
            *(short8*)&AH[row * LD1 + seg] = *(const short8*)(zh  + ga);
            *(short8*)&AL[row * LD1 + seg] = *(const short8*)(zl  + ga);
            *(short8*)&BH[row * LD1 + seg] = *(const short8*)(cbh + gb);
            *(short8*)&BL[row * LD1 + seg] = *(const short8*)(cbl + gb);
        }
        __syncthreads();

        short8 ah[4], al[4], bh[4], bl[4];
        #pragma unroll
        for (int mt = 0; mt < 4; ++mt) {
            const int row = wm + mt * 16 + lrow;
            ah[mt] = *(const short8*)&AH[row * LD1 + lq * 8];
            al[mt] = *(const short8*)&AL[row * LD1 + lq * 8];
        }
        #pragma unroll
        for (int nt = 0; nt < 4; ++nt) {
            const int row = wn + nt * 16 + lrow;
            bh[nt] = *(const short8*)&BH[row * LD1 + lq * 8];
            bl[nt] = *(const short8*)&BL[row * LD1 + lq * 8];
        }
        #pragma unroll
        for (int mt = 0; mt < 4; ++mt)
            #pragma unroll
            for (int nt = 0; nt < 4; ++nt) {
                acc[mt][nt] = __builtin_amdgcn_mfma_f32_16x16x32_bf16(ah[mt], bh[nt], acc[mt][nt], 0, 0, 0);
                acc[mt][nt] = __builtin_amdgcn_mfma_f32_16x16x32_bf16(ah[mt], bl[nt], acc[mt][nt], 0, 0, 0);
                acc[mt][nt] = __builtin_amdgcn_mfma_f32_16x16x32_bf16(al[mt], bh[nt], acc[mt][nt], 0, 0, 0);
            }
    }

    const float wq = 0.5f / fmaxf(var_q[0], 1e-10f);
    #pragma unroll
    for (int nt = 0; nt < 4; ++nt) {
        const int gcol = n0 + wn + nt * 16 + lrow;
        const float cn = cnorm[gcol];
        #pragma unroll
        for (int mt = 0; mt < 4; ++mt) {
            #pragma unroll
            for (int r = 0; r < 4; ++r) {
                const int grow = m0 + wm + mt * 16 + lq * 4 + r;
                logit[(size_t)grow * KCODES + gcol] = wq * (2.0f * acc[mt][nt][r] - cn);
            }
        }
    }
}

// ---------------- K3: fused stats + colsum + encodings ----------------
// Block b handles row pairs (r, r+2048), r = b*8..b*8+7.  One threefry per
// column serves BOTH rows.  Per-thread cols: t*4 + j*1024 (+e), j=0..7.
// Colsum partials accumulate in regs, spill to part[b][8192] (reused zh/zl).
#define PROCESS_ROW(rr, garr)                                               \
  {                                                                         \
    const int rowi = (rr);                                                  \
    const float* lrowp = logit + (size_t)rowi * KCODES;                     \
    float l[32];                                                            \
    _Pragma("unroll")                                                       \
    for (int j = 0; j < 8; ++j) {                                           \
        float4 v = *(const float4*)(lrowp + t * 4 + j * 1024);              \
        l[j*4+0] = v.x; l[j*4+1] = v.y; l[j*4+2] = v.z; l[j*4+3] = v.w;     \
    }                                                                       \
    float m1 = -3.0e38f, m2 = -3.0e38f;                                     \
    _Pragma("unroll")                                                       \
    for (int e = 0; e < 32; ++e) {                                          \
        m1 = fmaxf(m1, l[e]);                                               \
        m2 = fmaxf(m2, (l[e] + garr[e]) * 2.0f);                            \
    }                                                                       \
    red2max(m1, m2, red);                                                   \
    float s1 = 0.f, t1 = 0.f, s2 = 0.f;                                     \
    _Pragma("unroll")                                                       \
    for (int e = 0; e < 32; ++e) {                                          \
        float x  = l[e] - m1;                                               \
        float e1 = __expf(x);                                               \
        s1 += e1; t1 += e1 * x;                                             \
        s2 += __expf((l[e] + garr[e]) * 2.0f - m2);                         \
    }                                                                       \
    red3sum(s1, t1, s2, red);                                               \
    const float is1 = 1.0f / s1, is2 = 1.0f / s2;                           \
    unsigned short o16[32];                                                 \
    _Pragma("unroll")                                                       \
    for (int e = 0; e < 32; ++e) {                                          \
        csum[e] += __expf(l[e] - m1) * is1;                                 \
        o16[e] = f2bf(__expf((l[e] + garr[e]) * 2.0f - m2) * is2);          \
    }                                                                       \
    unsigned short* dst = (unsigned short*)logit + (size_t)rowi * (2 * KCODES); \
    _Pragma("unroll")                                                       \
    for (int j = 0; j < 8; ++j)                                             \
        *(ushort4*)(dst + t * 4 + j * 1024) = *(ushort4*)&o16[j * 4];       \
    if (t == 0) kld += t1 * is1 - __logf(s1);                               \
  }

__global__ __launch_bounds__(256) void k_fused(float* __restrict__ logit,
                                               float* __restrict__ part,
                                               float* __restrict__ acc) {
    __shared__ float red[12];
    __shared__ float ghi[KCODES];   // pending gumbels for row r+2048
    const int b = blockIdx.x;       // 0..255
    const int t = threadIdx.x;
    float csum[32];
    #pragma unroll
    for (int e = 0; e < 32; ++e) csum[e] = 0.f;
    float kld = 0.f;

    for (int i = 0; i < 8; ++i) {
        const int r_lo = b * 8 + i;       // < 2048
        const int r_hi = r_lo + 2048;

        float g_lo[32];
        #pragma unroll
        for (int j = 0; j < 8; ++j)
            #pragma unroll
            for (int e4 = 0; e4 < 4; ++e4) {
                const uint32_t col = (uint32_t)(t * 4 + j * 1024 + e4);
                const uint32_t jg  = (uint32_t)r_lo * (uint32_t)KCODES + col;
                uint32_t b0, b1;
                threefry2(jg, jg + HALF_NK, b0, b1);
                g_lo[j*4+e4] = gum(b0);
                ghi[col] = gum(b1);        // thread-private slot, no barrier needed
            }

        PROCESS_ROW(r_lo, g_lo)

        float g_hi[32];
        #pragma unroll
        for (int j = 0; j < 8; ++j)
            #pragma unroll
            for (int e4 = 0; e4 < 4; ++e4)
                g_hi[j*4+e4] = ghi[t * 4 + j * 1024 + e4];

        PROCESS_ROW(r_hi, g_hi)
    }

    #pragma unroll
    for (int j = 0; j < 8; ++j)
        *(float4*)&part[(size_t)b * KCODES + t * 4 + j * 1024] =
            make_float4(csum[j*4], csum[j*4+1], csum[j*4+2], csum[j*4+3]);
    if (t == 0) atomicAdd(acc + 0, kld);
}

// ---------------- K4: reduce colsum partials -> entropy ----------------
__global__ __launch_bounds__(256) void k_colred(const float* __restrict__ part,
                                                float* __restrict__ acc) {
    __shared__ float red[4];
    const int col = blockIdx.x * 256 + threadIdx.x;
    float s = 0.f;
    for (int bb = 0; bb < 256; ++bb)
        s += part[(size_t)bb * KCODES + col];
    float a = s * INV_N;
    float ent = a * __logf(a + 1e-7f);
    ent = blockReduce1(ent, red);
    if (threadIdx.x == 0) atomicAdd(acc + 2, ent);
}

// ---------------- K6: GEMM2 z_hat = enc16 @ cbT^T (K-split, atomic out) ----
#define BK2 64
__global__ __launch_bounds__(256) void k_gemm2(const unsigned short* __restrict__ enc16,
                                               const unsigned short* __restrict__ cbT,
                                               float* __restrict__ out) {
    __shared__ __align__(16) unsigned short AS[64 * BK2];
    const int t    = threadIdx.x;
    const int n0   = blockIdx.x * 256;
    const int m0   = blockIdx.y * 64;
    const int kz0  = blockIdx.z * (KCODES / 4);
    const int w    = t >> 6;
    const int lane = t & 63;
    const int wn   = w * 64;
    const int lrow = lane & 15;
    const int lq   = lane >> 4;

    f32x4 acc[4][4];
    #pragma unroll
    for (int i = 0; i < 4; ++i)
        #pragma unroll
        for (int j = 0; j < 4; ++j)
            acc[i][j] = (f32x4){0.f, 0.f, 0.f, 0.f};

    for (int kt = kz0; kt < kz0 + KCODES / 4; kt += BK2) {
        __syncthreads();
        #pragma unroll
        for (int j = 0; j < 2; ++j) {
            const int unit = t + j * 256;
            const int row  = unit >> 3;
            const int seg  = (unit & 7) * 8;
            *(short8*)&AS[row * BK2 + seg] =
                *(const short8*)(enc16 + (size_t)(m0 + row) * (2 * KCODES) + kt + seg);
        }
        __syncthreads();
        #pragma unroll
        for (int chunk = 0; chunk < 2; ++chunk) {
            short8 af[4];
            #pragma unroll
            for (int mt = 0; mt < 4; ++mt)
                af[mt] = *(const short8*)&AS[(mt * 16 + lrow) * BK2 + chunk * 32 + lq * 8];
            #pragma unroll
            for (int nt = 0; nt < 4; ++nt) {
                const short8 bf = *(const short8*)(cbT
                    + (size_t)(n0 + wn + nt * 16 + lrow) * KCODES + kt + chunk * 32 + lq * 8);
                #pragma unroll
                for (int mt = 0; mt < 4; ++mt)
                    acc[mt][nt] = __builtin_amdgcn_mfma_f32_16x16x32_bf16(af[mt], bf, acc[mt][nt], 0, 0, 0);
            }
        }
    }

    #pragma unroll
    for (int mt = 0; mt < 4; ++mt)
        #pragma unroll
        for (int nt = 0; nt < 4; ++nt)
            #pragma unroll
            for (int r = 0; r < 4; ++r) {
                const int grow = m0 + mt * 16 + lq * 4 + r;
                const int gcol = n0 + wn + nt * 16 + lrow;
                atomicAdd(&out[(size_t)grow * DDIM + gcol], acc[mt][nt][r]);
            }
}

// ---------------- K6b: continuous-KLD partial ----------------
__global__ __launch_bounds__(256) void k_loss2(const float* __restrict__ z,
                                               const float* __restrict__ out,
                                               float* __restrict__ acc) {
    __shared__ float red[4];
    const size_t idx = ((size_t)blockIdx.x * 256 + threadIdx.x) * 4;
    float4 zv = *(const float4*)(z + idx);
    float4 ov = *(const float4*)(out + idx);
    float dx = zv.x - ov.x, dy = zv.y - ov.y, dz = zv.z - ov.z, dw = zv.w - ov.w;
    float part = dx*dx + dy*dy + dz*dz + dw*dw;
    part = blockReduce1(part, red);
    if (threadIdx.x == 0) atomicAdd(acc + 1, part);
}

// ---------------- K7: finalize ----------------
__global__ __launch_bounds__(64) void k_final(const float* __restrict__ acc,
                                              const float* __restrict__ var_q,
                                              float* __restrict__ out) {
    if (threadIdx.x == 0) {
        float w = 0.5f / fmaxf(var_q[0], 1e-10f);
        float loss = acc[0] / BS_F + acc[1] * w / BS_F;
        out[(size_t)N_ROWS * DDIM]     = loss;
        out[(size_t)N_ROWS * DDIM + 1] = expf(-acc[2]);
    }
}

// ---------------- launch ----------------
extern "C" void kernel_launch(void* const* d_in, const int* in_sizes, int n_in,
                              void* d_out, int out_size, void* d_ws, size_t ws_size,
                              hipStream_t stream) {
    const float* z     = (const float*)d_in[0];
    const float* var_q = (const float*)d_in[1];
    const float* cb    = (const float*)d_in[2];
    float* out = (float*)d_out;
    float* ws  = (float*)d_ws;
    if (ws_size < (size_t)WS_FLOATS * sizeof(float)) return;  // need ~168 MB

    float* logit  = ws + OFF_LOGIT;
    float* cnorm  = ws + OFF_CNORM;
    float* accp   = ws + OFF_ACC;
    unsigned short* zh  = (unsigned short*)(ws + OFF_ZH);
    unsigned short* zl  = (unsigned short*)(ws + OFF_ZL);
    unsigned short* cbh = (unsigned short*)(ws + OFF_CBH);
    unsigned short* cbl = (unsigned short*)(ws + OFF_CBL);
    unsigned short* cbT = (unsigned short*)(ws + OFF_CBT);
    float* part = ws + OFF_ZH;   // zh/zl reused after gemm1 (exactly 256*8192 floats)

    hipMemsetAsync(accp, 0, 4 * sizeof(float), stream);
    hipMemsetAsync(out, 0, (size_t)N_ROWS * DDIM * sizeof(float), stream);

    k_split <<<N_ROWS * DDIM / 2048, 256, 0, stream>>>(z, zh, zl);
    k_split <<<KCODES * DDIM / 2048, 256, 0, stream>>>(cb, cbh, cbl);
    k_cnorm <<<KCODES, 64, 0, stream>>>(cb, cnorm);
    k_trans <<<dim3(KCODES / 64, DDIM / 64), 256, 0, stream>>>(cb, cbT);
    k_gemm1 <<<dim3(KCODES / 128, N_ROWS / 128), 256, 0, stream>>>(zh, zl, cbh, cbl, cnorm, var_q, logit);
    k_fused <<<256, 256, 0, stream>>>(logit, part, accp);
    k_gemm2 <<<dim3(DDIM / 256, N_ROWS / 64, 4), 256, 0, stream>>>((const unsigned short*)logit, cbT, out);
    k_colred<<<KCODES / 256, 256, 0, stream>>>(part, accp);
    k_loss2 <<<N_ROWS * DDIM / 1024, 256, 0, stream>>>(z, out, accp);
    k_final <<<1, 64, 0, stream>>>(accp, var_q, out);
}

// Round 5
// 441.115 us; speedup vs baseline: 2.8550x; 1.0285x over previous
//
#include <hip/hip_runtime.h>
#include <stdint.h>

// ---------------- problem constants ----------------
#define N_ROWS 4096      // bs*seq = 8*512
#define DDIM   512
#define KCODES 8192
#define NK     (N_ROWS * KCODES)   // 33,554,432
#define HALF_NK 16777216u
#define BS_F   8.0f
#define INV_N  (1.0f / 4096.0f)

// ---------------- ws layout (float offsets) ----------------
// logit region (NK floats) also hosts the in-place bf16 encodings:
// row n's bf16 encodings live in the first 16KB of row n's 32KB slot.
// zh/zl/cbh/cbl (6.3M floats, 25.2MB) are DEAD after k_gemm1 ->
// reused as colsum partials [512][8192] (16.8MB).
#define OFF_LOGIT   0
#define OFF_CNORM   (NK)
#define OFF_ACC     (OFF_CNORM + KCODES)   // [0]=sum p*logp, [1]=sum (z-zhat)^2, [2]=entropy
#define OFF_ZH      (OFF_ACC + 4)                    // bf16 z hi  [4096*512]
#define OFF_ZL      (OFF_ZH + (N_ROWS*DDIM/2))       // bf16 z lo
#define OFF_CBH     (OFF_ZL + (N_ROWS*DDIM/2))       // bf16 cb hi [8192*512]
#define OFF_CBL     (OFF_CBH + (KCODES*DDIM/2))      // bf16 cb lo
#define OFF_CBT     (OFF_CBL + (KCODES*DDIM/2))      // bf16 cb^T  [512*8192]
#define WS_FLOATS   (OFF_CBT + (DDIM*KCODES/2))      // ~168MB

typedef __attribute__((ext_vector_type(8))) short short8;
typedef __attribute__((ext_vector_type(4))) float f32x4;

__device__ __forceinline__ unsigned short f2bf(float x) {
    uint32_t u = __float_as_uint(x);
    u += 0x7fffu + ((u >> 16) & 1u);
    return (unsigned short)(u >> 16);
}

// async global->LDS, 16B per lane; lds base must be wave-uniform,
// lane i lands at lds + i*16 (no padding allowed in the chunk).
__device__ __forceinline__ void cp16(const unsigned short* g, unsigned short* l) {
    __builtin_amdgcn_global_load_lds(
        (const __attribute__((address_space(1))) void*)g,
        (__attribute__((address_space(3))) void*)l, 16, 0, 0);
}

// ---------------- JAX threefry2x32-20, key(42) = (0,42) ----------------
__device__ __forceinline__ uint32_t rotl32(uint32_t x, int r) {
    return (x << r) | (x >> (32 - r));
}

// one threefry block -> BOTH outputs (counters c0,c1)
__device__ __forceinline__ void threefry2(uint32_t c0, uint32_t c1,
                                          uint32_t& o0, uint32_t& o1) {
    const uint32_t ks0 = 0u, ks1 = 42u, ks2 = 0x1BD11BDAu ^ 0u ^ 42u;
    uint32_t x0 = c0 + ks0;
    uint32_t x1 = c1 + ks1;
#define TF_R(r) { x0 += x1; x1 = rotl32(x1, r); x1 ^= x0; }
    TF_R(13) TF_R(15) TF_R(26) TF_R(6)
    x0 += ks1; x1 += ks2 + 1u;
    TF_R(17) TF_R(29) TF_R(16) TF_R(24)
    x0 += ks2; x1 += ks0 + 2u;
    TF_R(13) TF_R(15) TF_R(26) TF_R(6)
    x0 += ks0; x1 += ks1 + 3u;
    TF_R(17) TF_R(29) TF_R(16) TF_R(24)
    x0 += ks1; x1 += ks2 + 4u;
    TF_R(13) TF_R(15) TF_R(26) TF_R(6)
    x0 += ks2; x1 += ks0 + 5u;
#undef TF_R
    o0 = x0; o1 = x1;
}

__device__ __forceinline__ float u01(uint32_t bits) {
    return __uint_as_float((bits >> 9) | 0x3f800000u) - 1.0f;
}

__device__ __forceinline__ float gum(uint32_t bits) {
    float u = u01(bits);
    return -__logf(-__logf(u + 1e-10f) + 1e-10f);
}

// ---------------- block reduce helpers (256 threads = 4 waves) ----------------
__device__ __forceinline__ float blockReduce1(float v, float* red) {
    #pragma unroll
    for (int o = 32; o > 0; o >>= 1) v += __shfl_down(v, o);
    __syncthreads();
    if ((threadIdx.x & 63) == 0) red[threadIdx.x >> 6] = v;
    __syncthreads();
    return red[0] + red[1] + red[2] + red[3];
}

__device__ __forceinline__ void red2max(float& a, float& b, float* red) {
    #pragma unroll
    for (int o = 32; o > 0; o >>= 1) {
        a = fmaxf(a, __shfl_down(a, o));
        b = fmaxf(b, __shfl_down(b, o));
    }
    __syncthreads();
    if ((threadIdx.x & 63) == 0) {
        red[(threadIdx.x >> 6) * 2 + 0] = a;
        red[(threadIdx.x >> 6) * 2 + 1] = b;
    }
    __syncthreads();
    a = fmaxf(fmaxf(red[0], red[2]), fmaxf(red[4], red[6]));
    b = fmaxf(fmaxf(red[1], red[3]), fmaxf(red[5], red[7]));
}

__device__ __forceinline__ void red3sum(float& a, float& b, float& c, float* red) {
    #pragma unroll
    for (int o = 32; o > 0; o >>= 1) {
        a += __shfl_down(a, o);
        b += __shfl_down(b, o);
        c += __shfl_down(c, o);
    }
    __syncthreads();
    if ((threadIdx.x & 63) == 0) {
        red[(threadIdx.x >> 6) * 3 + 0] = a;
        red[(threadIdx.x >> 6) * 3 + 1] = b;
        red[(threadIdx.x >> 6) * 3 + 2] = c;
    }
    __syncthreads();
    a = red[0] + red[3] + red[6] + red[9];
    b = red[1] + red[4] + red[7] + red[10];
    c = red[2] + red[5] + red[8] + red[11];
}

// ---------------- P1: split -> bf16 hi/lo ----------------
__global__ __launch_bounds__(256) void k_split(const float* __restrict__ src,
                                               unsigned short* __restrict__ hi,
                                               unsigned short* __restrict__ lo) {
    const size_t idx = ((size_t)blockIdx.x * 256 + threadIdx.x) * 8;
    float4 a = *(const float4*)(src + idx);
    float4 b = *(const float4*)(src + idx + 4);
    float f[8] = {a.x, a.y, a.z, a.w, b.x, b.y, b.z, b.w};
    unsigned short h8[8], l8[8];
    #pragma unroll
    for (int e = 0; e < 8; ++e) {
        unsigned short h = f2bf(f[e]);
        float hf = __uint_as_float((uint32_t)h << 16);
        h8[e] = h;
        l8[e] = f2bf(f[e] - hf);
    }
    *(short8*)(hi + idx) = *(short8*)h8;
    *(short8*)(lo + idx) = *(short8*)l8;
}

// ---------------- P2: codebook row norms ----------------
__global__ __launch_bounds__(64) void k_cnorm(const float* __restrict__ cb,
                                              float* __restrict__ cnorm) {
    const int k = blockIdx.x;
    const int lane = threadIdx.x;
    const float* row = cb + (size_t)k * DDIM;
    float4 a = *(const float4*)(row + lane * 4);
    float4 b = *(const float4*)(row + 256 + lane * 4);
    float s = a.x*a.x + a.y*a.y + a.z*a.z + a.w*a.w
            + b.x*b.x + b.y*b.y + b.z*b.z + b.w*b.w;
    #pragma unroll
    for (int o = 32; o > 0; o >>= 1) s += __shfl_down(s, o);
    if (lane == 0) cnorm[k] = s;
}

// ---------------- P3: cb[k][d] -> cbT bf16 [d][k] ----------------
__global__ __launch_bounds__(256) void k_trans(const float* __restrict__ cb,
                                               unsigned short* __restrict__ cbT) {
    __shared__ unsigned short TT[64][65];
    const int t  = threadIdx.x;
    const int k0 = blockIdx.x * 64;
    const int d0 = blockIdx.y * 64;
    #pragma unroll
    for (int j = 0; j < 4; ++j) {
        const int unit = t + j * 256;
        const int r = unit >> 4;
        const int s = unit & 15;
        float4 v = *(const float4*)(cb + (size_t)(k0 + r) * DDIM + d0 + s * 4);
        TT[r][s*4+0] = f2bf(v.x); TT[r][s*4+1] = f2bf(v.y);
        TT[r][s*4+2] = f2bf(v.z); TT[r][s*4+3] = f2bf(v.w);
    }
    __syncthreads();
    #pragma unroll
    for (int j = 0; j < 2; ++j) {
        const int unit = t + j * 256;
        const int dr = unit >> 3;
        const int ks = (unit & 7) * 8;
        unsigned short o8[8];
        #pragma unroll
        for (int i = 0; i < 8; ++i) o8[i] = TT[ks + i][dr];
        *(short8*)(cbT + (size_t)(d0 + dr) * KCODES + k0 + ks) = *(short8*)o8;
    }
}

// ---------------- K2: GEMM1 (MFMA, async LDS staging, bf16 3-term) ----------
// 128x128 tile, BK=32. LDS row stride 32 shorts = 64B (forced by the
// global_load_lds lane*16 contiguity rule; bank padding is a dead lever --
// wave64 b128 reads are 8-cycle minimum regardless of layout, measured R4).
// Wave w stages array w (zh/zl/cbh/cbl) via 8 x 16B wave-loads/iter.
#define BK1 32
__global__ __launch_bounds__(256) void k_gemm1(const unsigned short* __restrict__ zh,
                                               const unsigned short* __restrict__ zl,
                                               const unsigned short* __restrict__ cbh,
                                               const unsigned short* __restrict__ cbl,
                                               const float* __restrict__ cnorm,
                                               const float* __restrict__ var_q,
                                               float* __restrict__ logit) {
    __shared__ __align__(16) unsigned short AH[128 * BK1];
    __shared__ __align__(16) unsigned short AL[128 * BK1];
    __shared__ __align__(16) unsigned short BH[128 * BK1];
    __shared__ __align__(16) unsigned short BL[128 * BK1];
    const int t    = threadIdx.x;
    const int n0   = blockIdx.x * 128;
    const int m0   = blockIdx.y * 128;
    const int w    = t >> 6;
    const int lane = t & 63;
    const int wm   = (w >> 1) * 64;
    const int wn   = (w & 1) * 64;
    const int lrow = lane & 15;
    const int lq   = lane >> 4;

    // staging assignment: wave w owns one array
    const unsigned short* src;
    unsigned short* dst;
    if      (w == 0) { src = zh;  dst = AH; }
    else if (w == 1) { src = zl;  dst = AL; }
    else if (w == 2) { src = cbh; dst = BH; }
    else             { src = cbl; dst = BL; }
    const int brow = (w < 2) ? m0 : n0;
    // lane -> (row = lane>>2, 16B granule = lane&3) within a 16-row chunk
    const unsigned short* gsrc = src + (size_t)(brow + (lane >> 2)) * DDIM + (lane & 3) * 8;

    f32x4 acc[4][4];
    #pragma unroll
    for (int i = 0; i < 4; ++i)
        #pragma unroll
        for (int j = 0; j < 4; ++j)
            acc[i][j] = (f32x4){0.f, 0.f, 0.f, 0.f};

    for (int kt = 0; kt < DDIM; kt += BK1) {
        __syncthreads();   // previous iter's fragment reads done
        #pragma unroll
        for (int j = 0; j < 8; ++j)
            cp16(gsrc + (size_t)j * 16 * DDIM + kt, dst + j * 512);
        __syncthreads();   // drains vmcnt (compiler emits vmcnt(0) before barrier)

        short8 ah[4], al[4], bh[4], bl[4];
        #pragma unroll
        for (int mt = 0; mt < 4; ++mt) {
            const int row = wm + mt * 16 + lrow;
            ah[mt] = *(const short8*)&AH[row * BK1 + lq * 8];
            al[mt] = *(const short8*)&AL[row * BK1 + lq * 8];
        }
        #pragma unroll
        for (int nt = 0; nt < 4; ++nt) {
            const int row = wn + nt * 16 + lrow;
            bh[nt] = *(const short8*)&BH[row * BK1 + lq * 8];
            bl[nt] = *(const short8*)&BL[row * BK1 + lq * 8];
        }
        #pragma unroll
        for (int mt = 0; mt < 4; ++mt)
            #pragma unroll
            for (int nt = 0; nt < 4; ++nt) {
                acc[mt][nt] = __builtin_amdgcn_mfma_f32_16x16x32_bf16(ah[mt], bh[nt], acc[mt][nt], 0, 0, 0);
                acc[mt][nt] = __builtin_amdgcn_mfma_f32_16x16x32_bf16(ah[mt], bl[nt], acc[mt][nt], 0, 0, 0);
                acc[mt][nt] = __builtin_amdgcn_mfma_f32_16x16x32_bf16(al[mt], bh[nt], acc[mt][nt], 0, 0, 0);
            }
    }

    const float wq = 0.5f / fmaxf(var_q[0], 1e-10f);
    #pragma unroll
    for (int nt = 0; nt < 4; ++nt) {
        const int gcol = n0 + wn + nt * 16 + lrow;
        const float cn = cnorm[gcol];
        #pragma unroll
        for (int mt = 0; mt < 4; ++mt) {
            #pragma unroll
            for (int r = 0; r < 4; ++r) {
                const int grow = m0 + wm + mt * 16 + lq * 4 + r;
                logit[(size_t)grow * KCODES + gcol] = wq * (2.0f * acc[mt][nt][r] - cn);
            }
        }
    }
}

// ---------------- K3: fused stats + colsum + encodings ----------------
// Block b handles 4 row pairs (r, r+2048), r = b*4..b*4+3.  One threefry per
// column serves BOTH rows.  2 exps/element: e1,e2 stored back into l[]/g[].
// Colsum partials spill to part[b][8192] (reused zh..cbl region, 512 blocks).
#define PROCESS_ROW(rr, garr)                                               \
  {                                                                         \
    const int rowi = (rr);                                                  \
    const float* lrowp = logit + (size_t)rowi * KCODES;                     \
    float l[32];                                                            \
    _Pragma("unroll")                                                       \
    for (int j = 0; j < 8; ++j) {                                           \
        float4 v = *(const float4*)(lrowp + t * 4 + j * 1024);              \
        l[j*4+0] = v.x; l[j*4+1] = v.y; l[j*4+2] = v.z; l[j*4+3] = v.w;     \
    }                                                                       \
    float m1 = -3.0e38f, m2 = -3.0e38f;                                     \
    _Pragma("unroll")                                                       \
    for (int e = 0; e < 32; ++e) {                                          \
        m1 = fmaxf(m1, l[e]);                                               \
        m2 = fmaxf(m2, (l[e] + garr[e]) * 2.0f);                            \
    }                                                                       \
    red2max(m1, m2, red);                                                   \
    float s1 = 0.f, t1 = 0.f, s2 = 0.f;                                     \
    _Pragma("unroll")                                                       \
    for (int e = 0; e < 32; ++e) {                                          \
        float x  = l[e] - m1;                                               \
        float y  = (l[e] + garr[e]) * 2.0f - m2;                            \
        float e1 = __expf(x);                                               \
        float e2 = __expf(y);                                               \
        s1 += e1; t1 += e1 * x; s2 += e2;                                   \
        l[e] = e1; garr[e] = e2;                                            \
    }                                                                       \
    red3sum(s1, t1, s2, red);                                               \
    const float is1 = 1.0f / s1, is2 = 1.0f / s2;                           \
    unsigned short o16[32];                                                 \
    _Pragma("unroll")                                                       \
    for (int e = 0; e < 32; ++e) {                                          \
        csum[e] += l[e] * is1;                                              \
        o16[e] = f2bf(garr[e] * is2);                                       \
    }                                                                       \
    unsigned short* dstp = (unsigned short*)logit + (size_t)rowi * (2 * KCODES); \
    _Pragma("unroll")                                                       \
    for (int j = 0; j < 8; ++j)                                             \
        *(ushort4*)(dstp + t * 4 + j * 1024) = *(ushort4*)&o16[j * 4];      \
    if (t == 0) kld += t1 * is1 - __logf(s1);                               \
  }

__global__ __launch_bounds__(256) void k_fused(float* __restrict__ logit,
                                               float* __restrict__ part,
                                               float* __restrict__ acc) {
    __shared__ float red[12];
    __shared__ float ghi[KCODES];   // pending gumbels for row r+2048
    const int b = blockIdx.x;       // 0..511
    const int t = threadIdx.x;
    float csum[32];
    #pragma unroll
    for (int e = 0; e < 32; ++e) csum[e] = 0.f;
    float kld = 0.f;

    for (int i = 0; i < 4; ++i) {
        const int r_lo = b * 4 + i;       // < 2048
        const int r_hi = r_lo + 2048;

        float g_lo[32];
        #pragma unroll
        for (int j = 0; j < 8; ++j)
            #pragma unroll
            for (int e4 = 0; e4 < 4; ++e4) {
                const uint32_t col = (uint32_t)(t * 4 + j * 1024 + e4);
                const uint32_t jg  = (uint32_t)r_lo * (uint32_t)KCODES + col;
                uint32_t b0, b1;
                threefry2(jg, jg + HALF_NK, b0, b1);
                g_lo[j*4+e4] = gum(b0);
                ghi[col] = gum(b1);        // thread-private slot, no barrier needed
            }

        PROCESS_ROW(r_lo, g_lo)

        float g_hi[32];
        #pragma unroll
        for (int j = 0; j < 8; ++j)
            #pragma unroll
            for (int e4 = 0; e4 < 4; ++e4)
                g_hi[j*4+e4] = ghi[t * 4 + j * 1024 + e4];

        PROCESS_ROW(r_hi, g_hi)
    }

    #pragma unroll
    for (int j = 0; j < 8; ++j)
        *(float4*)&part[(size_t)b * KCODES + t * 4 + j * 1024] =
            make_float4(csum[j*4], csum[j*4+1], csum[j*4+2], csum[j*4+3]);
    if (t == 0) atomicAdd(acc + 0, kld);
}

// ---------------- K4: reduce colsum partials -> entropy ----------------
__global__ __launch_bounds__(256) void k_colred(const float* __restrict__ part,
                                                float* __restrict__ acc) {
    __shared__ float red[4];
    const int col = blockIdx.x * 256 + threadIdx.x;
    float s = 0.f;
    for (int bb = 0; bb < 512; ++bb)
        s += part[(size_t)bb * KCODES + col];
    float a = s * INV_N;
    float ent = a * __logf(a + 1e-7f);
    ent = blockReduce1(ent, red);
    if (threadIdx.x == 0) atomicAdd(acc + 2, ent);
}

// ---------------- K6: GEMM2 z_hat = enc16 @ cbT^T (K-split, atomic out) ----
#define BK2 64
__global__ __launch_bounds__(256) void k_gemm2(const unsigned short* __restrict__ enc16,
                                               const unsigned short* __restrict__ cbT,
                                               float* __restrict__ out) {
    __shared__ __align__(16) unsigned short AS[64 * BK2];
    const int t    = threadIdx.x;
    const int n0   = blockIdx.x * 256;
    const int m0   = blockIdx.y * 64;
    const int kz0  = blockIdx.z * (KCODES / 4);
    const int w    = t >> 6;
    const int lane = t & 63;
    const int wn   = w * 64;
    const int lrow = lane & 15;
    const int lq   = lane >> 4;

    f32x4 acc[4][4];
    #pragma unroll
    for (int i = 0; i < 4; ++i)
        #pragma unroll
        for (int j = 0; j < 4; ++j)
            acc[i][j] = (f32x4){0.f, 0.f, 0.f, 0.f};

    for (int kt = kz0; kt < kz0 + KCODES / 4; kt += BK2) {
        __syncthreads();
        #pragma unroll
        for (int j = 0; j < 2; ++j) {
            const int unit = t + j * 256;
            const int row  = unit >> 3;
            const int seg  = (unit & 7) * 8;
            *(short8*)&AS[row * BK2 + seg] =
                *(const short8*)(enc16 + (size_t)(m0 + row) * (2 * KCODES) + kt + seg);
        }
        __syncthreads();
        #pragma unroll
        for (int chunk = 0; chunk < 2; ++chunk) {
            short8 af[4];
            #pragma unroll
            for (int mt = 0; mt < 4; ++mt)
                af[mt] = *(const short8*)&AS[(mt * 16 + lrow) * BK2 + chunk * 32 + lq * 8];
            #pragma unroll
            for (int nt = 0; nt < 4; ++nt) {
                const short8 bf = *(const short8*)(cbT
                    + (size_t)(n0 + wn + nt * 16 + lrow) * KCODES + kt + chunk * 32 + lq * 8);
                #pragma unroll
                for (int mt = 0; mt < 4; ++mt)
                    acc[mt][nt] = __builtin_amdgcn_mfma_f32_16x16x32_bf16(af[mt], bf, acc[mt][nt], 0, 0, 0);
            }
        }
    }

    #pragma unroll
    for (int mt = 0; mt < 4; ++mt)
        #pragma unroll
        for (int nt = 0; nt < 4; ++nt)
            #pragma unroll
            for (int r = 0; r < 4; ++r) {
                const int grow = m0 + mt * 16 + lq * 4 + r;
                const int gcol = n0 + wn + nt * 16 + lrow;
                atomicAdd(&out[(size_t)grow * DDIM + gcol], acc[mt][nt][r]);
            }
}

// ---------------- K6b: continuous-KLD partial ----------------
__global__ __launch_bounds__(256) void k_loss2(const float* __restrict__ z,
                                               const float* __restrict__ out,
                                               float* __restrict__ acc) {
    __shared__ float red[4];
    const size_t idx = ((size_t)blockIdx.x * 256 + threadIdx.x) * 4;
    float4 zv = *(const float4*)(z + idx);
    float4 ov = *(const float4*)(out + idx);
    float dx = zv.x - ov.x, dy = zv.y - ov.y, dz = zv.z - ov.z, dw = zv.w - ov.w;
    float part = dx*dx + dy*dy + dz*dz + dw*dw;
    part = blockReduce1(part, red);
    if (threadIdx.x == 0) atomicAdd(acc + 1, part);
}

// ---------------- K7: finalize ----------------
__global__ __launch_bounds__(64) void k_final(const float* __restrict__ acc,
                                              const float* __restrict__ var_q,
                                              float* __restrict__ out) {
    if (threadIdx.x == 0) {
        float w = 0.5f / fmaxf(var_q[0], 1e-10f);
        float loss = acc[0] / BS_F + acc[1] * w / BS_F;
        out[(size_t)N_ROWS * DDIM]     = loss;
        out[(size_t)N_ROWS * DDIM + 1] = expf(-acc[2]);
    }
}

// ---------------- launch ----------------
extern "C" void kernel_launch(void* const* d_in, const int* in_sizes, int n_in,
                              void* d_out, int out_size, void* d_ws, size_t ws_size,
                              hipStream_t stream) {
    const float* z     = (const float*)d_in[0];
    const float* var_q = (const float*)d_in[1];
    const float* cb    = (const float*)d_in[2];
    float* out = (float*)d_out;
    float* ws  = (float*)d_ws;
    if (ws_size < (size_t)WS_FLOATS * sizeof(float)) return;  // need ~168 MB

    float* logit  = ws + OFF_LOGIT;
    float* cnorm  = ws + OFF_CNORM;
    float* accp   = ws + OFF_ACC;
    unsigned short* zh  = (unsigned short*)(ws + OFF_ZH);
    unsigned short* zl  = (unsigned short*)(ws + OFF_ZL);
    unsigned short* cbh = (unsigned short*)(ws + OFF_CBH);
    unsigned short* cbl = (unsigned short*)(ws + OFF_CBL);
    unsigned short* cbT = (unsigned short*)(ws + OFF_CBT);
    float* part = ws + OFF_ZH;   // zh..cbl reused after gemm1 (25.2MB >= 512*8192*4B)

    hipMemsetAsync(accp, 0, 4 * sizeof(float), stream);
    hipMemsetAsync(out, 0, (size_t)N_ROWS * DDIM * sizeof(float), stream);

    k_split <<<N_ROWS * DDIM / 2048, 256, 0, stream>>>(z, zh, zl);
    k_split <<<KCODES * DDIM / 2048, 256, 0, stream>>>(cb, cbh, cbl);
    k_cnorm <<<KCODES, 64, 0, stream>>>(cb, cnorm);
    k_trans <<<dim3(KCODES / 64, DDIM / 64), 256, 0, stream>>>(cb, cbT);
    k_gemm1 <<<dim3(KCODES / 128, N_ROWS / 128), 256, 0, stream>>>(zh, zl, cbh, cbl, cnorm, var_q, logit);
    k_fused <<<512, 256, 0, stream>>>(logit, part, accp);
    k_gemm2 <<<dim3(DDIM / 256, N_ROWS / 64, 4), 256, 0, stream>>>((const unsigned short*)logit, cbT, out);
    k_colred<<<KCODES / 256, 256, 0, stream>>>(part, accp);
    k_loss2 <<<N_ROWS * DDIM / 1024, 256, 0, stream>>>(z, out, accp);
    k_final <<<1, 64, 0, stream>>>(accp, var_q, out);
}

// Round 6
// 438.397 us; speedup vs baseline: 2.8727x; 1.0062x over previous
//
#include <hip/hip_runtime.h>
#include <stdint.h>

// ---------------- problem constants ----------------
#define N_ROWS 4096      // bs*seq = 8*512
#define DDIM   512
#define KCODES 8192
#define NK     (N_ROWS * KCODES)   // 33,554,432
#define HALF_NK 16777216u
#define BS_F   8.0f
#define INV_N  (1.0f / 4096.0f)

// ---------------- ws layout (float offsets) ----------------
// logit region (NK floats) also hosts the in-place bf16 encodings:
// row n's bf16 encodings live in the first 16KB of row n's 32KB slot.
// zh/zl/cbh/cbl (6.3M floats, 25.2MB) are DEAD after k_gemm1 ->
// reused as colsum partials [512][8192] (16.8MB).
#define OFF_LOGIT   0
#define OFF_CNORM   (NK)
#define OFF_ACC     (OFF_CNORM + KCODES)   // [0]=sum p*logp, [1]=sum (z-zhat)^2, [2]=entropy
#define OFF_ZH      (OFF_ACC + 4)                    // bf16 z hi  [4096*512]
#define OFF_ZL      (OFF_ZH + (N_ROWS*DDIM/2))       // bf16 z lo
#define OFF_CBH     (OFF_ZL + (N_ROWS*DDIM/2))       // bf16 cb hi [8192*512]
#define OFF_CBL     (OFF_CBH + (KCODES*DDIM/2))      // bf16 cb lo
#define OFF_CBT     (OFF_CBL + (KCODES*DDIM/2))      // bf16 cb^T  [512*8192]
#define WS_FLOATS   (OFF_CBT + (DDIM*KCODES/2))      // ~168MB

typedef __attribute__((ext_vector_type(8))) short short8;
typedef __attribute__((ext_vector_type(4))) float f32x4;

__device__ __forceinline__ unsigned short f2bf(float x) {
    uint32_t u = __float_as_uint(x);
    u += 0x7fffu + ((u >> 16) & 1u);
    return (unsigned short)(u >> 16);
}

// async global->LDS, 16B per lane; lds base must be wave-uniform,
// lane i lands at lds + i*16 (no padding allowed in the chunk).
__device__ __forceinline__ void cp16(const unsigned short* g, unsigned short* l) {
    __builtin_amdgcn_global_load_lds(
        (const __attribute__((address_space(1))) void*)g,
        (__attribute__((address_space(3))) void*)l, 16, 0, 0);
}

// ---------------- JAX threefry2x32-20, key(42) = (0,42) ----------------
__device__ __forceinline__ uint32_t rotl32(uint32_t x, int r) {
    return (x << r) | (x >> (32 - r));
}

// one threefry block -> BOTH outputs (counters c0,c1)
__device__ __forceinline__ void threefry2(uint32_t c0, uint32_t c1,
                                          uint32_t& o0, uint32_t& o1) {
    const uint32_t ks0 = 0u, ks1 = 42u, ks2 = 0x1BD11BDAu ^ 0u ^ 42u;
    uint32_t x0 = c0 + ks0;
    uint32_t x1 = c1 + ks1;
#define TF_R(r) { x0 += x1; x1 = rotl32(x1, r); x1 ^= x0; }
    TF_R(13) TF_R(15) TF_R(26) TF_R(6)
    x0 += ks1; x1 += ks2 + 1u;
    TF_R(17) TF_R(29) TF_R(16) TF_R(24)
    x0 += ks2; x1 += ks0 + 2u;
    TF_R(13) TF_R(15) TF_R(26) TF_R(6)
    x0 += ks0; x1 += ks1 + 3u;
    TF_R(17) TF_R(29) TF_R(16) TF_R(24)
    x0 += ks1; x1 += ks2 + 4u;
    TF_R(13) TF_R(15) TF_R(26) TF_R(6)
    x0 += ks2; x1 += ks0 + 5u;
#undef TF_R
    o0 = x0; o1 = x1;
}

__device__ __forceinline__ float u01(uint32_t bits) {
    return __uint_as_float((bits >> 9) | 0x3f800000u) - 1.0f;
}

__device__ __forceinline__ float gum(uint32_t bits) {
    float u = u01(bits);
    return -__logf(-__logf(u + 1e-10f) + 1e-10f);
}

// ---------------- block reduce helpers (256 threads = 4 waves) ----------------
__device__ __forceinline__ float blockReduce1(float v, float* red) {
    #pragma unroll
    for (int o = 32; o > 0; o >>= 1) v += __shfl_down(v, o);
    __syncthreads();
    if ((threadIdx.x & 63) == 0) red[threadIdx.x >> 6] = v;
    __syncthreads();
    return red[0] + red[1] + red[2] + red[3];
}

__device__ __forceinline__ void red2max(float& a, float& b, float* red) {
    #pragma unroll
    for (int o = 32; o > 0; o >>= 1) {
        a = fmaxf(a, __shfl_down(a, o));
        b = fmaxf(b, __shfl_down(b, o));
    }
    __syncthreads();
    if ((threadIdx.x & 63) == 0) {
        red[(threadIdx.x >> 6) * 2 + 0] = a;
        red[(threadIdx.x >> 6) * 2 + 1] = b;
    }
    __syncthreads();
    a = fmaxf(fmaxf(red[0], red[2]), fmaxf(red[4], red[6]));
    b = fmaxf(fmaxf(red[1], red[3]), fmaxf(red[5], red[7]));
}

__device__ __forceinline__ void red3sum(float& a, float& b, float& c, float* red) {
    #pragma unroll
    for (int o = 32; o > 0; o >>= 1) {
        a += __shfl_down(a, o);
        b += __shfl_down(b, o);
        c += __shfl_down(c, o);
    }
    __syncthreads();
    if ((threadIdx.x & 63) == 0) {
        red[(threadIdx.x >> 6) * 3 + 0] = a;
        red[(threadIdx.x >> 6) * 3 + 1] = b;
        red[(threadIdx.x >> 6) * 3 + 2] = c;
    }
    __syncthreads();
    a = red[0] + red[3] + red[6] + red[9];
    b = red[1] + red[4] + red[7] + red[10];
    c = red[2] + red[5] + red[8] + red[11];
}

// ---------------- P1: split -> bf16 hi/lo ----------------
__global__ __launch_bounds__(256) void k_split(const float* __restrict__ src,
                                               unsigned short* __restrict__ hi,
                                               unsigned short* __restrict__ lo) {
    const size_t idx = ((size_t)blockIdx.x * 256 + threadIdx.x) * 8;
    float4 a = *(const float4*)(src + idx);
    float4 b = *(const float4*)(src + idx + 4);
    float f[8] = {a.x, a.y, a.z, a.w, b.x, b.y, b.z, b.w};
    unsigned short h8[8], l8[8];
    #pragma unroll
    for (int e = 0; e < 8; ++e) {
        unsigned short h = f2bf(f[e]);
        float hf = __uint_as_float((uint32_t)h << 16);
        h8[e] = h;
        l8[e] = f2bf(f[e] - hf);
    }
    *(short8*)(hi + idx) = *(short8*)h8;
    *(short8*)(lo + idx) = *(short8*)l8;
}

// ---------------- P2: codebook row norms ----------------
__global__ __launch_bounds__(64) void k_cnorm(const float* __restrict__ cb,
                                              float* __restrict__ cnorm) {
    const int k = blockIdx.x;
    const int lane = threadIdx.x;
    const float* row = cb + (size_t)k * DDIM;
    float4 a = *(const float4*)(row + lane * 4);
    float4 b = *(const float4*)(row + 256 + lane * 4);
    float s = a.x*a.x + a.y*a.y + a.z*a.z + a.w*a.w
            + b.x*b.x + b.y*b.y + b.z*b.z + b.w*b.w;
    #pragma unroll
    for (int o = 32; o > 0; o >>= 1) s += __shfl_down(s, o);
    if (lane == 0) cnorm[k] = s;
}

// ---------------- P3: cb[k][d] -> cbT bf16 [d][k] ----------------
__global__ __launch_bounds__(256) void k_trans(const float* __restrict__ cb,
                                               unsigned short* __restrict__ cbT) {
    __shared__ unsigned short TT[64][65];
    const int t  = threadIdx.x;
    const int k0 = blockIdx.x * 64;
    const int d0 = blockIdx.y * 64;
    #pragma unroll
    for (int j = 0; j < 4; ++j) {
        const int unit = t + j * 256;
        const int r = unit >> 4;
        const int s = unit & 15;
        float4 v = *(const float4*)(cb + (size_t)(k0 + r) * DDIM + d0 + s * 4);
        TT[r][s*4+0] = f2bf(v.x); TT[r][s*4+1] = f2bf(v.y);
        TT[r][s*4+2] = f2bf(v.z); TT[r][s*4+3] = f2bf(v.w);
    }
    __syncthreads();
    #pragma unroll
    for (int j = 0; j < 2; ++j) {
        const int unit = t + j * 256;
        const int dr = unit >> 3;
        const int ks = (unit & 7) * 8;
        unsigned short o8[8];
        #pragma unroll
        for (int i = 0; i < 8; ++i) o8[i] = TT[ks + i][dr];
        *(short8*)(cbT + (size_t)(d0 + dr) * KCODES + k0 + ks) = *(short8*)o8;
    }
}

// ---------------- K2: GEMM1 (MFMA, async LDS staging, bf16 3-term) ----------
// 128x128 tile, BK=32.  At the m97-structure plateau (~35% of bf16 ceiling);
// further tweaks measured dead (R4: pad, R5: async staging).  Kept as-is.
#define BK1 32
__global__ __launch_bounds__(256) void k_gemm1(const unsigned short* __restrict__ zh,
                                               const unsigned short* __restrict__ zl,
                                               const unsigned short* __restrict__ cbh,
                                               const unsigned short* __restrict__ cbl,
                                               const float* __restrict__ cnorm,
                                               const float* __restrict__ var_q,
                                               float* __restrict__ logit) {
    __shared__ __align__(16) unsigned short AH[128 * BK1];
    __shared__ __align__(16) unsigned short AL[128 * BK1];
    __shared__ __align__(16) unsigned short BH[128 * BK1];
    __shared__ __align__(16) unsigned short BL[128 * BK1];
    const int t    = threadIdx.x;
    const int n0   = blockIdx.x * 128;
    const int m0   = blockIdx.y * 128;
    const int w    = t >> 6;
    const int lane = t & 63;
    const int wm   = (w >> 1) * 64;
    const int wn   = (w & 1) * 64;
    const int lrow = lane & 15;
    const int lq   = lane >> 4;

    const unsigned short* src;
    unsigned short* dst;
    if      (w == 0) { src = zh;  dst = AH; }
    else if (w == 1) { src = zl;  dst = AL; }
    else if (w == 2) { src = cbh; dst = BH; }
    else             { src = cbl; dst = BL; }
    const int brow = (w < 2) ? m0 : n0;
    const unsigned short* gsrc = src + (size_t)(brow + (lane >> 2)) * DDIM + (lane & 3) * 8;

    f32x4 acc[4][4];
    #pragma unroll
    for (int i = 0; i < 4; ++i)
        #pragma unroll
        for (int j = 0; j < 4; ++j)
            acc[i][j] = (f32x4){0.f, 0.f, 0.f, 0.f};

    for (int kt = 0; kt < DDIM; kt += BK1) {
        __syncthreads();
        #pragma unroll
        for (int j = 0; j < 8; ++j)
            cp16(gsrc + (size_t)j * 16 * DDIM + kt, dst + j * 512);
        __syncthreads();

        short8 ah[4], al[4], bh[4], bl[4];
        #pragma unroll
        for (int mt = 0; mt < 4; ++mt) {
            const int row = wm + mt * 16 + lrow;
            ah[mt] = *(const short8*)&AH[row * BK1 + lq * 8];
            al[mt] = *(const short8*)&AL[row * BK1 + lq * 8];
        }
        #pragma unroll
        for (int nt = 0; nt < 4; ++nt) {
            const int row = wn + nt * 16 + lrow;
            bh[nt] = *(const short8*)&BH[row * BK1 + lq * 8];
            bl[nt] = *(const short8*)&BL[row * BK1 + lq * 8];
        }
        #pragma unroll
        for (int mt = 0; mt < 4; ++mt)
            #pragma unroll
            for (int nt = 0; nt < 4; ++nt) {
                acc[mt][nt] = __builtin_amdgcn_mfma_f32_16x16x32_bf16(ah[mt], bh[nt], acc[mt][nt], 0, 0, 0);
                acc[mt][nt] = __builtin_amdgcn_mfma_f32_16x16x32_bf16(ah[mt], bl[nt], acc[mt][nt], 0, 0, 0);
                acc[mt][nt] = __builtin_amdgcn_mfma_f32_16x16x32_bf16(al[mt], bh[nt], acc[mt][nt], 0, 0, 0);
            }
    }

    const float wq = 0.5f / fmaxf(var_q[0], 1e-10f);
    #pragma unroll
    for (int nt = 0; nt < 4; ++nt) {
        const int gcol = n0 + wn + nt * 16 + lrow;
        const float cn = cnorm[gcol];
        #pragma unroll
        for (int mt = 0; mt < 4; ++mt) {
            #pragma unroll
            for (int r = 0; r < 4; ++r) {
                const int grow = m0 + wm + mt * 16 + lq * 4 + r;
                logit[(size_t)grow * KCODES + gcol] = wq * (2.0f * acc[mt][nt][r] - cn);
            }
        }
    }
}

// ---------------- K3: fused stats + colsum + encodings ----------------
#define PROCESS_ROW(rr, garr)                                               \
  {                                                                         \
    const int rowi = (rr);                                                  \
    const float* lrowp = logit + (size_t)rowi * KCODES;                     \
    float l[32];                                                            \
    _Pragma("unroll")                                                       \
    for (int j = 0; j < 8; ++j) {                                           \
        float4 v = *(const float4*)(lrowp + t * 4 + j * 1024);              \
        l[j*4+0] = v.x; l[j*4+1] = v.y; l[j*4+2] = v.z; l[j*4+3] = v.w;     \
    }                                                                       \
    float m1 = -3.0e38f, m2 = -3.0e38f;                                     \
    _Pragma("unroll")                                                       \
    for (int e = 0; e < 32; ++e) {                                          \
        m1 = fmaxf(m1, l[e]);                                               \
        m2 = fmaxf(m2, (l[e] + garr[e]) * 2.0f);                            \
    }                                                                       \
    red2max(m1, m2, red);                                                   \
    float s1 = 0.f, t1 = 0.f, s2 = 0.f;                                     \
    _Pragma("unroll")                                                       \
    for (int e = 0; e < 32; ++e) {                                          \
        float x  = l[e] - m1;                                               \
        float y  = (l[e] + garr[e]) * 2.0f - m2;                            \
        float e1 = __expf(x);                                               \
        float e2 = __expf(y);                                               \
        s1 += e1; t1 += e1 * x; s2 += e2;                                   \
        l[e] = e1; garr[e] = e2;                                            \
    }                                                                       \
    red3sum(s1, t1, s2, red);                                               \
    const float is1 = 1.0f / s1, is2 = 1.0f / s2;                           \
    unsigned short o16[32];                                                 \
    _Pragma("unroll")                                                       \
    for (int e = 0; e < 32; ++e) {                                          \
        csum[e] += l[e] * is1;                                              \
        o16[e] = f2bf(garr[e] * is2);                                       \
    }                                                                       \
    unsigned short* dstp = (unsigned short*)logit + (size_t)rowi * (2 * KCODES); \
    _Pragma("unroll")                                                       \
    for (int j = 0; j < 8; ++j)                                             \
        *(ushort4*)(dstp + t * 4 + j * 1024) = *(ushort4*)&o16[j * 4];      \
    if (t == 0) kld += t1 * is1 - __logf(s1);                               \
  }

__global__ __launch_bounds__(256) void k_fused(float* __restrict__ logit,
                                               float* __restrict__ part,
                                               float* __restrict__ acc) {
    __shared__ float red[12];
    __shared__ float ghi[KCODES];   // pending gumbels for row r+2048
    const int b = blockIdx.x;       // 0..511
    const int t = threadIdx.x;
    float csum[32];
    #pragma unroll
    for (int e = 0; e < 32; ++e) csum[e] = 0.f;
    float kld = 0.f;

    for (int i = 0; i < 4; ++i) {
        const int r_lo = b * 4 + i;       // < 2048
        const int r_hi = r_lo + 2048;

        float g_lo[32];
        #pragma unroll
        for (int j = 0; j < 8; ++j)
            #pragma unroll
            for (int e4 = 0; e4 < 4; ++e4) {
                const uint32_t col = (uint32_t)(t * 4 + j * 1024 + e4);
                const uint32_t jg  = (uint32_t)r_lo * (uint32_t)KCODES + col;
                uint32_t b0, b1;
                threefry2(jg, jg + HALF_NK, b0, b1);
                g_lo[j*4+e4] = gum(b0);
                ghi[col] = gum(b1);
            }

        PROCESS_ROW(r_lo, g_lo)

        float g_hi[32];
        #pragma unroll
        for (int j = 0; j < 8; ++j)
            #pragma unroll
            for (int e4 = 0; e4 < 4; ++e4)
                g_hi[j*4+e4] = ghi[t * 4 + j * 1024 + e4];

        PROCESS_ROW(r_hi, g_hi)
    }

    #pragma unroll
    for (int j = 0; j < 8; ++j)
        *(float4*)&part[(size_t)b * KCODES + t * 4 + j * 1024] =
            make_float4(csum[j*4], csum[j*4+1], csum[j*4+2], csum[j*4+3]);
    if (t == 0) atomicAdd(acc + 0, kld);
}

// ---------------- K4: reduce colsum partials -> entropy ----------------
__global__ __launch_bounds__(256) void k_colred(const float* __restrict__ part,
                                                float* __restrict__ acc) {
    __shared__ float red[4];
    const int col = blockIdx.x * 256 + threadIdx.x;
    float s = 0.f;
    for (int bb = 0; bb < 512; ++bb)
        s += part[(size_t)bb * KCODES + col];
    float a = s * INV_N;
    float ent = a * __logf(a + 1e-7f);
    ent = blockReduce1(ent, red);
    if (threadIdx.x == 0) atomicAdd(acc + 2, ent);
}

// ---------------- K6: GEMM2 z_hat = enc16 @ cbT^T ----------------
// LDS-staged A (8KB) and B (16KB) via global_load_lds width=16.
// Tile 64 rows x 128 cols, BK=64, ksplit=2 -> 512 blocks (2/CU).
// Waves 2x2: wave tile 32x64 (2mt x 4nt of 16x16).
#define BK2 64
__global__ __launch_bounds__(256) void k_gemm2(const unsigned short* __restrict__ enc16,
                                               const unsigned short* __restrict__ cbT,
                                               float* __restrict__ out) {
    __shared__ __align__(16) unsigned short AS[64 * BK2];    // 8 KB
    __shared__ __align__(16) unsigned short BS[128 * BK2];   // 16 KB
    const int t    = threadIdx.x;
    const int n0   = blockIdx.x * 128;          // grid.x = 4
    const int m0   = blockIdx.y * 64;           // grid.y = 64
    const int kz0  = blockIdx.z * (KCODES / 2); // ksplit 2
    const int w    = t >> 6;
    const int lane = t & 63;
    const int wm   = (w >> 1) * 32;
    const int wn   = (w & 1) * 64;
    const int lrow = lane & 15;
    const int lq   = lane >> 4;
    const int srow = lane >> 3;        // staging row 0..7 within 8-row chunk
    const int scol = (lane & 7) * 8;   // staging k-offset (shorts)

    // per-lane staging sources (chunk-of-8-rows base added per cp16)
    const unsigned short* Asrc = enc16 + (size_t)(m0 + srow) * (2 * KCODES) + scol;
    const unsigned short* Bsrc = cbT   + (size_t)(n0 + srow) * KCODES + scol;

    f32x4 acc[2][4];
    #pragma unroll
    for (int i = 0; i < 2; ++i)
        #pragma unroll
        for (int j = 0; j < 4; ++j)
            acc[i][j] = (f32x4){0.f, 0.f, 0.f, 0.f};

    for (int kt = kz0; kt < kz0 + KCODES / 2; kt += BK2) {
        __syncthreads();
        // A: 8 x 1KB cp16 (wave w does 2), rows ja*8..ja*8+7
        #pragma unroll
        for (int j = 0; j < 2; ++j) {
            const int ja = w * 2 + j;
            cp16(Asrc + (size_t)(ja * 8) * (2 * KCODES) + kt, AS + ja * 512);
        }
        // B: 16 x 1KB cp16 (wave w does 4)
        #pragma unroll
        for (int j = 0; j < 4; ++j) {
            const int jb = w * 4 + j;
            cp16(Bsrc + (size_t)(jb * 8) * KCODES + kt, BS + jb * 512);
        }
        __syncthreads();

        #pragma unroll
        for (int chunk = 0; chunk < 2; ++chunk) {
            short8 af[2];
            #pragma unroll
            for (int mt = 0; mt < 2; ++mt)
                af[mt] = *(const short8*)&AS[(wm + mt * 16 + lrow) * BK2 + chunk * 32 + lq * 8];
            #pragma unroll
            for (int nt = 0; nt < 4; ++nt) {
                const short8 bf = *(const short8*)&BS[(wn + nt * 16 + lrow) * BK2 + chunk * 32 + lq * 8];
                #pragma unroll
                for (int mt = 0; mt < 2; ++mt)
                    acc[mt][nt] = __builtin_amdgcn_mfma_f32_16x16x32_bf16(af[mt], bf, acc[mt][nt], 0, 0, 0);
            }
        }
    }

    #pragma unroll
    for (int mt = 0; mt < 2; ++mt)
        #pragma unroll
        for (int nt = 0; nt < 4; ++nt)
            #pragma unroll
            for (int r = 0; r < 4; ++r) {
                const int grow = m0 + wm + mt * 16 + lq * 4 + r;
                const int gcol = n0 + wn + nt * 16 + lrow;
                atomicAdd(&out[(size_t)grow * DDIM + gcol], acc[mt][nt][r]);
            }
}

// ---------------- K6b: continuous-KLD partial ----------------
__global__ __launch_bounds__(256) void k_loss2(const float* __restrict__ z,
                                               const float* __restrict__ out,
                                               float* __restrict__ acc) {
    __shared__ float red[4];
    const size_t idx = ((size_t)blockIdx.x * 256 + threadIdx.x) * 4;
    float4 zv = *(const float4*)(z + idx);
    float4 ov = *(const float4*)(out + idx);
    float dx = zv.x - ov.x, dy = zv.y - ov.y, dz = zv.z - ov.z, dw = zv.w - ov.w;
    float part = dx*dx + dy*dy + dz*dz + dw*dw;
    part = blockReduce1(part, red);
    if (threadIdx.x == 0) atomicAdd(acc + 1, part);
}

// ---------------- K7: finalize ----------------
__global__ __launch_bounds__(64) void k_final(const float* __restrict__ acc,
                                              const float* __restrict__ var_q,
                                              float* __restrict__ out) {
    if (threadIdx.x == 0) {
        float w = 0.5f / fmaxf(var_q[0], 1e-10f);
        float loss = acc[0] / BS_F + acc[1] * w / BS_F;
        out[(size_t)N_ROWS * DDIM]     = loss;
        out[(size_t)N_ROWS * DDIM + 1] = expf(-acc[2]);
    }
}

// ---------------- launch ----------------
extern "C" void kernel_launch(void* const* d_in, const int* in_sizes, int n_in,
                              void* d_out, int out_size, void* d_ws, size_t ws_size,
                              hipStream_t stream) {
    const float* z     = (const float*)d_in[0];
    const float* var_q = (const float*)d_in[1];
    const float* cb    = (const float*)d_in[2];
    float* out = (float*)d_out;
    float* ws  = (float*)d_ws;
    if (ws_size < (size_t)WS_FLOATS * sizeof(float)) return;  // need ~168 MB

    float* logit  = ws + OFF_LOGIT;
    float* cnorm  = ws + OFF_CNORM;
    float* accp   = ws + OFF_ACC;
    unsigned short* zh  = (unsigned short*)(ws + OFF_ZH);
    unsigned short* zl  = (unsigned short*)(ws + OFF_ZL);
    unsigned short* cbh = (unsigned short*)(ws + OFF_CBH);
    unsigned short* cbl = (unsigned short*)(ws + OFF_CBL);
    unsigned short* cbT = (unsigned short*)(ws + OFF_CBT);
    float* part = ws + OFF_ZH;   // zh..cbl reused after gemm1 (25.2MB >= 512*8192*4B)

    hipMemsetAsync(accp, 0, 4 * sizeof(float), stream);
    hipMemsetAsync(out, 0, (size_t)N_ROWS * DDIM * sizeof(float), stream);

    k_split <<<N_ROWS * DDIM / 2048, 256, 0, stream>>>(z, zh, zl);
    k_split <<<KCODES * DDIM / 2048, 256, 0, stream>>>(cb, cbh, cbl);
    k_cnorm <<<KCODES, 64, 0, stream>>>(cb, cnorm);
    k_trans <<<dim3(KCODES / 64, DDIM / 64), 256, 0, stream>>>(cb, cbT);
    k_gemm1 <<<dim3(KCODES / 128, N_ROWS / 128), 256, 0, stream>>>(zh, zl, cbh, cbl, cnorm, var_q, logit);
    k_fused <<<512, 256, 0, stream>>>(logit, part, accp);
    k_gemm2 <<<dim3(DDIM / 128, N_ROWS / 64, 2), 256, 0, stream>>>((const unsigned short*)logit, cbT, out);
    k_colred<<<KCODES / 256, 256, 0, stream>>>(part, accp);
    k_loss2 <<<N_ROWS * DDIM / 1024, 256, 0, stream>>>(z, out, accp);
    k_final <<<1, 64, 0, stream>>>(accp, var_q, out);
}

// Round 8
// 402.402 us; speedup vs baseline: 3.1297x; 1.0894x over previous
//
#include <hip/hip_runtime.h>
#include <stdint.h>

// ---------------- problem constants ----------------
#define N_ROWS 4096      // bs*seq = 8*512
#define DDIM   512
#define KCODES 8192
#define NK     (N_ROWS * KCODES)   // 33,554,432
#define HALF_NK 16777216u
#define BS_F   8.0f
#define INV_N  (1.0f / 4096.0f)

// ---------------- ws layout (float offsets) ----------------
// logit region (NK floats) also hosts the in-place bf16 encodings:
// row n's bf16 encodings live in the first 16KB of row n's 32KB slot.
// After k_gemm1: zh/zl/cbh (16MB) reused as colsum partials [512][8192];
// cbl (8MB) reused as outA (gemm2 k-split partial 0).
#define OFF_LOGIT   0
#define OFF_CNORM   (NK)
#define OFF_ACC     (OFF_CNORM + KCODES)   // [0]=sum p*logp, [1]=sum (z-zhat)^2, [2]=entropy
#define OFF_ZH      (OFF_ACC + 4)                    // bf16 z hi  [4096*512]
#define OFF_ZL      (OFF_ZH + (N_ROWS*DDIM/2))       // bf16 z lo
#define OFF_CBH     (OFF_ZL + (N_ROWS*DDIM/2))       // bf16 cb hi [8192*512]
#define OFF_CBL     (OFF_CBH + (KCODES*DDIM/2))      // bf16 cb lo
#define OFF_CBT     (OFF_CBL + (KCODES*DDIM/2))      // bf16 cb^T  [512*8192]
#define WS_FLOATS   (OFF_CBT + (DDIM*KCODES/2))      // ~168MB

typedef __attribute__((ext_vector_type(8))) short short8;
typedef __attribute__((ext_vector_type(4))) float f32x4;

__device__ __forceinline__ unsigned short f2bf(float x) {
    uint32_t u = __float_as_uint(x);
    u += 0x7fffu + ((u >> 16) & 1u);
    return (unsigned short)(u >> 16);
}

// async global->LDS, 16B per lane; lds base must be wave-uniform,
// lane i lands at lds + i*16 (no padding allowed in the chunk).
__device__ __forceinline__ void cp16(const unsigned short* g, unsigned short* l) {
    __builtin_amdgcn_global_load_lds(
        (const __attribute__((address_space(1))) void*)g,
        (__attribute__((address_space(3))) void*)l, 16, 0, 0);
}

// ---------------- JAX threefry2x32-20, key(42) = (0,42) ----------------
__device__ __forceinline__ uint32_t rotl32(uint32_t x, int r) {
    return (x << r) | (x >> (32 - r));
}

// one threefry block -> BOTH outputs (counters c0,c1)
__device__ __forceinline__ void threefry2(uint32_t c0, uint32_t c1,
                                          uint32_t& o0, uint32_t& o1) {
    const uint32_t ks0 = 0u, ks1 = 42u, ks2 = 0x1BD11BDAu ^ 0u ^ 42u;
    uint32_t x0 = c0 + ks0;
    uint32_t x1 = c1 + ks1;
#define TF_R(r) { x0 += x1; x1 = rotl32(x1, r); x1 ^= x0; }
    TF_R(13) TF_R(15) TF_R(26) TF_R(6)
    x0 += ks1; x1 += ks2 + 1u;
    TF_R(17) TF_R(29) TF_R(16) TF_R(24)
    x0 += ks2; x1 += ks0 + 2u;
    TF_R(13) TF_R(15) TF_R(26) TF_R(6)
    x0 += ks0; x1 += ks1 + 3u;
    TF_R(17) TF_R(29) TF_R(16) TF_R(24)
    x0 += ks1; x1 += ks2 + 4u;
    TF_R(13) TF_R(15) TF_R(26) TF_R(6)
    x0 += ks2; x1 += ks0 + 5u;
#undef TF_R
    o0 = x0; o1 = x1;
}

__device__ __forceinline__ float u01(uint32_t bits) {
    return __uint_as_float((bits >> 9) | 0x3f800000u) - 1.0f;
}

__device__ __forceinline__ float gum(uint32_t bits) {
    float u = u01(bits);
    return -__logf(-__logf(u + 1e-10f) + 1e-10f);
}

// ---------------- block reduce helpers (256 threads = 4 waves) ----------------
__device__ __forceinline__ float blockReduce1(float v, float* red) {
    #pragma unroll
    for (int o = 32; o > 0; o >>= 1) v += __shfl_down(v, o);
    __syncthreads();
    if ((threadIdx.x & 63) == 0) red[threadIdx.x >> 6] = v;
    __syncthreads();
    return red[0] + red[1] + red[2] + red[3];
}

__device__ __forceinline__ void red2max(float& a, float& b, float* red) {
    #pragma unroll
    for (int o = 32; o > 0; o >>= 1) {
        a = fmaxf(a, __shfl_down(a, o));
        b = fmaxf(b, __shfl_down(b, o));
    }
    __syncthreads();
    if ((threadIdx.x & 63) == 0) {
        red[(threadIdx.x >> 6) * 2 + 0] = a;
        red[(threadIdx.x >> 6) * 2 + 1] = b;
    }
    __syncthreads();
    a = fmaxf(fmaxf(red[0], red[2]), fmaxf(red[4], red[6]));
    b = fmaxf(fmaxf(red[1], red[3]), fmaxf(red[5], red[7]));
}

__device__ __forceinline__ void red3sum(float& a, float& b, float& c, float* red) {
    #pragma unroll
    for (int o = 32; o > 0; o >>= 1) {
        a += __shfl_down(a, o);
        b += __shfl_down(b, o);
        c += __shfl_down(c, o);
    }
    __syncthreads();
    if ((threadIdx.x & 63) == 0) {
        red[(threadIdx.x >> 6) * 3 + 0] = a;
        red[(threadIdx.x >> 6) * 3 + 1] = b;
        red[(threadIdx.x >> 6) * 3 + 2] = c;
    }
    __syncthreads();
    a = red[0] + red[3] + red[6] + red[9];
    b = red[1] + red[4] + red[7] + red[10];
    c = red[2] + red[5] + red[8] + red[11];
}

// ---------------- K1: fused prep ----------------
// blocks [0,1024):    split z  -> zh/zl              (1024 * 2048 floats = 2M)
// blocks [1024,3072): split cb -> cbh/cbl + cnorm    (2048 * 2048 floats = 4.2M)
// blocks [3072,4096): transpose cb -> cbT bf16       (128 k-tiles x 8 d-tiles)
// block  4096:        zero accp
__global__ __launch_bounds__(256) void k_prep(const float* __restrict__ z,
                                              const float* __restrict__ cb,
                                              unsigned short* __restrict__ zh,
                                              unsigned short* __restrict__ zl,
                                              unsigned short* __restrict__ cbh,
                                              unsigned short* __restrict__ cbl,
                                              unsigned short* __restrict__ cbT,
                                              float* __restrict__ cnorm,
                                              float* __restrict__ accp) {
    __shared__ unsigned short TT[64][65];
    const int b = blockIdx.x;
    const int t = threadIdx.x;
    if (b < 3072) {
        const bool isz = (b < 1024);
        const int bb = isz ? b : b - 1024;
        const float* src = isz ? z : cb;
        unsigned short* hi = isz ? zh : cbh;
        unsigned short* lo = isz ? zl : cbl;
        const size_t idx = ((size_t)bb * 256 + t) * 8;
        float4 a = *(const float4*)(src + idx);
        float4 bv = *(const float4*)(src + idx + 4);
        float f[8] = {a.x, a.y, a.z, a.w, bv.x, bv.y, bv.z, bv.w};
        unsigned short h8[8], l8[8];
        float s = 0.f;
        #pragma unroll
        for (int e = 0; e < 8; ++e) {
            unsigned short h = f2bf(f[e]);
            float hf = __uint_as_float((uint32_t)h << 16);
            h8[e] = h;
            l8[e] = f2bf(f[e] - hf);
            s += f[e] * f[e];
        }
        *(short8*)(hi + idx) = *(short8*)h8;
        *(short8*)(lo + idx) = *(short8*)l8;
        if (!isz) {
            // each wave covers exactly one cb row (64 lanes x 8 floats = 512)
            #pragma unroll
            for (int o = 32; o > 0; o >>= 1) s += __shfl_down(s, o);
            if ((t & 63) == 0) cnorm[bb * 4 + (t >> 6)] = s;  // max 2047*4+3 = 8191
        }
    } else if (b < 4096) {
        const int b3 = b - 3072;
        const int k0 = (b3 & 127) * 64;
        const int d0 = (b3 >> 7) * 64;
        #pragma unroll
        for (int j = 0; j < 4; ++j) {
            const int unit = t + j * 256;
            const int r = unit >> 4;
            const int s4 = unit & 15;
            float4 v = *(const float4*)(cb + (size_t)(k0 + r) * DDIM + d0 + s4 * 4);
            TT[r][s4*4+0] = f2bf(v.x); TT[r][s4*4+1] = f2bf(v.y);
            TT[r][s4*4+2] = f2bf(v.z); TT[r][s4*4+3] = f2bf(v.w);
        }
        __syncthreads();
        #pragma unroll
        for (int j = 0; j < 2; ++j) {
            const int unit = t + j * 256;
            const int dr = unit >> 3;
            const int ks = (unit & 7) * 8;
            unsigned short o8[8];
            #pragma unroll
            for (int i = 0; i < 8; ++i) o8[i] = TT[ks + i][dr];
            *(short8*)(cbT + (size_t)(d0 + dr) * KCODES + k0 + ks) = *(short8*)o8;
        }
    } else {
        if (t < 4) accp[t] = 0.f;
    }
}

// ---------------- K2: GEMM1 (MFMA, async LDS staging, bf16 3-term) ----------
// 128x128 tile, BK=32.  At the m97-structure plateau (~30-35% of bf16
// ceiling); pad (R4) and async staging (R5) both measured neutral.  Parked.
#define BK1 32
__global__ __launch_bounds__(256) void k_gemm1(const unsigned short* __restrict__ zh,
                                               const unsigned short* __restrict__ zl,
                                               const unsigned short* __restrict__ cbh,
                                               const unsigned short* __restrict__ cbl,
                                               const float* __restrict__ cnorm,
                                               const float* __restrict__ var_q,
                                               float* __restrict__ logit) {
    __shared__ __align__(16) unsigned short AH[128 * BK1];
    __shared__ __align__(16) unsigned short AL[128 * BK1];
    __shared__ __align__(16) unsigned short BH[128 * BK1];
    __shared__ __align__(16) unsigned short BL[128 * BK1];
    const int t    = threadIdx.x;
    const int n0   = blockIdx.x * 128;
    const int m0   = blockIdx.y * 128;
    const int w    = t >> 6;
    const int lane = t & 63;
    const int wm   = (w >> 1) * 64;
    const int wn   = (w & 1) * 64;
    const int lrow = lane & 15;
    const int lq   = lane >> 4;

    const unsigned short* src;
    unsigned short* dst;
    if      (w == 0) { src = zh;  dst = AH; }
    else if (w == 1) { src = zl;  dst = AL; }
    else if (w == 2) { src = cbh; dst = BH; }
    else             { src = cbl; dst = BL; }
    const int brow = (w < 2) ? m0 : n0;
    const unsigned short* gsrc = src + (size_t)(brow + (lane >> 2)) * DDIM + (lane & 3) * 8;

    f32x4 acc[4][4];
    #pragma unroll
    for (int i = 0; i < 4; ++i)
        #pragma unroll
        for (int j = 0; j < 4; ++j)
            acc[i][j] = (f32x4){0.f, 0.f, 0.f, 0.f};

    for (int kt = 0; kt < DDIM; kt += BK1) {
        __syncthreads();
        #pragma unroll
        for (int j = 0; j < 8; ++j)
            cp16(gsrc + (size_t)j * 16 * DDIM + kt, dst + j * 512);
        __syncthreads();

        short8 ah[4], al[4], bh[4], bl[4];
        #pragma unroll
        for (int mt = 0; mt < 4; ++mt) {
            const int row = wm + mt * 16 + lrow;
            ah[mt] = *(const short8*)&AH[row * BK1 + lq * 8];
            al[mt] = *(const short8*)&AL[row * BK1 + lq * 8];
        }
        #pragma unroll
        for (int nt = 0; nt < 4; ++nt) {
            const int row = wn + nt * 16 + lrow;
            bh[nt] = *(const short8*)&BH[row * BK1 + lq * 8];
            bl[nt] = *(const short8*)&BL[row * BK1 + lq * 8];
        }
        #pragma unroll
        for (int mt = 0; mt < 4; ++mt)
            #pragma unroll
            for (int nt = 0; nt < 4; ++nt) {
                acc[mt][nt] = __builtin_amdgcn_mfma_f32_16x16x32_bf16(ah[mt], bh[nt], acc[mt][nt], 0, 0, 0);
                acc[mt][nt] = __builtin_amdgcn_mfma_f32_16x16x32_bf16(ah[mt], bl[nt], acc[mt][nt], 0, 0, 0);
                acc[mt][nt] = __builtin_amdgcn_mfma_f32_16x16x32_bf16(al[mt], bh[nt], acc[mt][nt], 0, 0, 0);
            }
    }

    const float wq = 0.5f / fmaxf(var_q[0], 1e-10f);
    #pragma unroll
    for (int nt = 0; nt < 4; ++nt) {
        const int gcol = n0 + wn + nt * 16 + lrow;
        const float cn = cnorm[gcol];
        #pragma unroll
        for (int mt = 0; mt < 4; ++mt) {
            #pragma unroll
            for (int r = 0; r < 4; ++r) {
                const int grow = m0 + wm + mt * 16 + lq * 4 + r;
                logit[(size_t)grow * KCODES + gcol] = wq * (2.0f * acc[mt][nt][r] - cn);
            }
        }
    }
}

// ---------------- K3: fused stats + colsum + encodings ----------------
#define PROCESS_ROW(rr, garr)                                               \
  {                                                                         \
    const int rowi = (rr);                                                  \
    const float* lrowp = logit + (size_t)rowi * KCODES;                     \
    float l[32];                                                            \
    _Pragma("unroll")                                                       \
    for (int j = 0; j < 8; ++j) {                                           \
        float4 v = *(const float4*)(lrowp + t * 4 + j * 1024);              \
        l[j*4+0] = v.x; l[j*4+1] = v.y; l[j*4+2] = v.z; l[j*4+3] = v.w;     \
    }                                                                       \
    float m1 = -3.0e38f, m2 = -3.0e38f;                                     \
    _Pragma("unroll")                                                       \
    for (int e = 0; e < 32; ++e) {                                          \
        m1 = fmaxf(m1, l[e]);                                               \
        m2 = fmaxf(m2, (l[e] + garr[e]) * 2.0f);                            \
    }                                                                       \
    red2max(m1, m2, red);                                                   \
    float s1 = 0.f, t1 = 0.f, s2 = 0.f;                                     \
    _Pragma("unroll")                                                       \
    for (int e = 0; e < 32; ++e) {                                          \
        float x  = l[e] - m1;                                               \
        float y  = (l[e] + garr[e]) * 2.0f - m2;                            \
        float e1 = __expf(x);                                               \
        float e2 = __expf(y);                                               \
        s1 += e1; t1 += e1 * x; s2 += e2;                                   \
        l[e] = e1; garr[e] = e2;                                            \
    }                                                                       \
    red3sum(s1, t1, s2, red);                                               \
    const float is1 = 1.0f / s1, is2 = 1.0f / s2;                           \
    unsigned short o16[32];                                                 \
    _Pragma("unroll")                                                       \
    for (int e = 0; e < 32; ++e) {                                          \
        csum[e] += l[e] * is1;                                              \
        o16[e] = f2bf(garr[e] * is2);                                       \
    }                                                                       \
    unsigned short* dstp = (unsigned short*)logit + (size_t)rowi * (2 * KCODES); \
    _Pragma("unroll")                                                       \
    for (int j = 0; j < 8; ++j)                                             \
        *(ushort4*)(dstp + t * 4 + j * 1024) = *(ushort4*)&o16[j * 4];      \
    if (t == 0) kld += t1 * is1 - __logf(s1);                               \
  }

__global__ __launch_bounds__(256) void k_fused(float* __restrict__ logit,
                                               float* __restrict__ part,
                                               float* __restrict__ acc) {
    __shared__ float red[12];
    __shared__ float ghi[KCODES];   // pending gumbels for row r+2048
    const int b = blockIdx.x;       // 0..511
    const int t = threadIdx.x;
    float csum[32];
    #pragma unroll
    for (int e = 0; e < 32; ++e) csum[e] = 0.f;
    float kld = 0.f;

    for (int i = 0; i < 4; ++i) {
        const int r_lo = b * 4 + i;       // < 2048
        const int r_hi = r_lo + 2048;

        float g_lo[32];
        #pragma unroll
        for (int j = 0; j < 8; ++j)
            #pragma unroll
            for (int e4 = 0; e4 < 4; ++e4) {
                const uint32_t col = (uint32_t)(t * 4 + j * 1024 + e4);
                const uint32_t jg  = (uint32_t)r_lo * (uint32_t)KCODES + col;
                uint32_t b0, b1;
                threefry2(jg, jg + HALF_NK, b0, b1);
                g_lo[j*4+e4] = gum(b0);
                ghi[col] = gum(b1);
            }

        PROCESS_ROW(r_lo, g_lo)

        float g_hi[32];
        #pragma unroll
        for (int j = 0; j < 8; ++j)
            #pragma unroll
            for (int e4 = 0; e4 < 4; ++e4)
                g_hi[j*4+e4] = ghi[t * 4 + j * 1024 + e4];

        PROCESS_ROW(r_hi, g_hi)
    }

    #pragma unroll
    for (int j = 0; j < 8; ++j)
        *(float4*)&part[(size_t)b * KCODES + t * 4 + j * 1024] =
            make_float4(csum[j*4], csum[j*4+1], csum[j*4+2], csum[j*4+3]);
    if (t == 0) atomicAdd(acc + 0, kld);
}

// ---------------- K4: GEMM2 z_hat = enc16 @ cbT^T ----------------
// LDS-staged A (8KB) and B (16KB) via global_load_lds width=16.
// Tile 64 rows x 128 cols, BK=64, ksplit=2 -> 512 blocks.
// z=0 stores partial to outA (scratch); z=1 stores partial to out.
// k_tail sums them -> no memset, no atomics.
#define BK2 64
__global__ __launch_bounds__(256) void k_gemm2(const unsigned short* __restrict__ enc16,
                                               const unsigned short* __restrict__ cbT,
                                               float* __restrict__ outA,
                                               float* __restrict__ out) {
    __shared__ __align__(16) unsigned short AS[64 * BK2];    // 8 KB
    __shared__ __align__(16) unsigned short BS[128 * BK2];   // 16 KB
    const int t    = threadIdx.x;
    const int n0   = blockIdx.x * 128;          // grid.x = 4
    const int m0   = blockIdx.y * 64;           // grid.y = 64
    const int kz0  = blockIdx.z * (KCODES / 2); // ksplit 2
    float* dstC    = blockIdx.z ? out : outA;
    const int w    = t >> 6;
    const int lane = t & 63;
    const int wm   = (w >> 1) * 32;
    const int wn   = (w & 1) * 64;
    const int lrow = lane & 15;
    const int lq   = lane >> 4;
    const int srow = lane >> 3;        // staging row 0..7 within 8-row chunk
    const int scol = (lane & 7) * 8;   // staging k-offset (shorts)

    const unsigned short* Asrc = enc16 + (size_t)(m0 + srow) * (2 * KCODES) + scol;
    const unsigned short* Bsrc = cbT   + (size_t)(n0 + srow) * KCODES + scol;

    f32x4 acc[2][4];
    #pragma unroll
    for (int i = 0; i < 2; ++i)
        #pragma unroll
        for (int j = 0; j < 4; ++j)
            acc[i][j] = (f32x4){0.f, 0.f, 0.f, 0.f};

    for (int kt = kz0; kt < kz0 + KCODES / 2; kt += BK2) {
        __syncthreads();
        #pragma unroll
        for (int j = 0; j < 2; ++j) {
            const int ja = w * 2 + j;
            cp16(Asrc + (size_t)(ja * 8) * (2 * KCODES) + kt, AS + ja * 512);
        }
        #pragma unroll
        for (int j = 0; j < 4; ++j) {
            const int jb = w * 4 + j;
            cp16(Bsrc + (size_t)(jb * 8) * KCODES + kt, BS + jb * 512);
        }
        __syncthreads();

        #pragma unroll
        for (int chunk = 0; chunk < 2; ++chunk) {
            short8 af[2];
            #pragma unroll
            for (int mt = 0; mt < 2; ++mt)
                af[mt] = *(const short8*)&AS[(wm + mt * 16 + lrow) * BK2 + chunk * 32 + lq * 8];
            #pragma unroll
            for (int nt = 0; nt < 4; ++nt) {
                const short8 bf = *(const short8*)&BS[(wn + nt * 16 + lrow) * BK2 + chunk * 32 + lq * 8];
                #pragma unroll
                for (int mt = 0; mt < 2; ++mt)
                    acc[mt][nt] = __builtin_amdgcn_mfma_f32_16x16x32_bf16(af[mt], bf, acc[mt][nt], 0, 0, 0);
            }
        }
    }

    #pragma unroll
    for (int mt = 0; mt < 2; ++mt)
        #pragma unroll
        for (int nt = 0; nt < 4; ++nt)
            #pragma unroll
            for (int r = 0; r < 4; ++r) {
                const int grow = m0 + wm + mt * 16 + lq * 4 + r;
                const int gcol = n0 + wn + nt * 16 + lrow;
                dstC[(size_t)grow * DDIM + gcol] = acc[mt][nt][r];
            }
}

// ---------------- K5: tail (colsum entropy + out-combine + cont. KLD) -------
// blocks [0,32): column-sum entropy over 512 partials
// blocks [32,544): out = out + outA, accumulate (z - out)^2
__global__ __launch_bounds__(256) void k_tail(const float* __restrict__ part,
                                              const float* __restrict__ z,
                                              const float* __restrict__ outA,
                                              float* __restrict__ out,
                                              float* __restrict__ acc) {
    __shared__ float red[4];
    const int b = blockIdx.x;
    const int t = threadIdx.x;
    if (b < 32) {
        const int col = b * 256 + t;
        float s = 0.f;
        for (int bb = 0; bb < 512; ++bb)
            s += part[(size_t)bb * KCODES + col];
        float a = s * INV_N;
        float ent = a * __logf(a + 1e-7f);
        ent = blockReduce1(ent, red);
        if (t == 0) atomicAdd(acc + 2, ent);
    } else {
        const size_t base = (size_t)(b - 32) * 4096 + t * 4;
        float p = 0.f;
        #pragma unroll
        for (int j = 0; j < 4; ++j) {
            const size_t idx = base + j * 1024;
            float4 o1 = *(const float4*)(out + idx);
            float4 o2 = *(const float4*)(outA + idx);
            float4 zv = *(const float4*)(z + idx);
            float4 s4;
            s4.x = o1.x + o2.x; s4.y = o1.y + o2.y;
            s4.z = o1.z + o2.z; s4.w = o1.w + o2.w;
            *(float4*)(out + idx) = s4;
            float dx = zv.x - s4.x, dy = zv.y - s4.y;
            float dz = zv.z - s4.z, dw = zv.w - s4.w;
            p += dx*dx + dy*dy + dz*dz + dw*dw;
        }
        p = blockReduce1(p, red);
        if (t == 0) atomicAdd(acc + 1, p);
    }
}

// ---------------- K6: finalize ----------------
__global__ __launch_bounds__(64) void k_final(const float* __restrict__ acc,
                                              const float* __restrict__ var_q,
                                              float* __restrict__ out) {
    if (threadIdx.x == 0) {
        float w = 0.5f / fmaxf(var_q[0], 1e-10f);
        float loss = acc[0] / BS_F + acc[1] * w / BS_F;
        out[(size_t)N_ROWS * DDIM]     = loss;
        out[(size_t)N_ROWS * DDIM + 1] = expf(-acc[2]);
    }
}

// ---------------- launch ----------------
extern "C" void kernel_launch(void* const* d_in, const int* in_sizes, int n_in,
                              void* d_out, int out_size, void* d_ws, size_t ws_size,
                              hipStream_t stream) {
    const float* z     = (const float*)d_in[0];
    const float* var_q = (const float*)d_in[1];
    const float* cb    = (const float*)d_in[2];
    float* out = (float*)d_out;
    float* ws  = (float*)d_ws;
    if (ws_size < (size_t)WS_FLOATS * sizeof(float)) return;  // need ~168 MB

    float* logit  = ws + OFF_LOGIT;
    float* cnorm  = ws + OFF_CNORM;
    float* accp   = ws + OFF_ACC;
    unsigned short* zh  = (unsigned short*)(ws + OFF_ZH);
    unsigned short* zl  = (unsigned short*)(ws + OFF_ZL);
    unsigned short* cbh = (unsigned short*)(ws + OFF_CBH);
    unsigned short* cbl = (unsigned short*)(ws + OFF_CBL);
    unsigned short* cbT = (unsigned short*)(ws + OFF_CBT);
    float* part = ws + OFF_ZH;    // zh+zl+cbh reused after gemm1 (16MB = 512*8192*4B)
    float* outA = ws + OFF_CBL;   // cbl reused after gemm1 (8MB = 4096*512*4B)

    k_prep  <<<4097, 256, 0, stream>>>(z, cb, zh, zl, cbh, cbl, cbT, cnorm, accp);
    k_gemm1 <<<dim3(KCODES / 128, N_ROWS / 128), 256, 0, stream>>>(zh, zl, cbh, cbl, cnorm, var_q, logit);
    k_fused <<<512, 256, 0, stream>>>(logit, part, accp);
    k_gemm2 <<<dim3(DDIM / 128, N_ROWS / 64, 2), 256, 0, stream>>>((const unsigned short*)logit, cbT, outA, out);
    k_tail  <<<544, 256, 0, stream>>>(part, z, outA, out, accp);
    k_final <<<1, 64, 0, stream>>>(accp, var_q, out);
}